// Round 2
// baseline (90723.798 us; speedup 1.0000x reference)
//
#include <hip/hip_runtime.h>
#include <math.h>

#define SHIFT_N 4

__device__ __forceinline__ float rsq_acc(float a) {
  float r = rsqrtf(a);
  return r * (1.5f - 0.5f * a * r * r);
}

// Swizzled [64][32] fp32 LDS tile accessor: logical col-group g (4 floats)
// stored at physical group g ^ (row&7). Keeps 16B alignment (b128-able),
// spreads banks for both row-broadcast and per-lane-row access patterns.
__device__ __forceinline__ float* tptr(float* base, int row, int g) {
  return base + row * 32 + ((g ^ (row & 7)) << 2);
}
__device__ __forceinline__ const float* tptrc(const float* base, int row, int g) {
  return base + row * 32 + ((g ^ (row & 7)) << 2);
}

// One block per 8x8 window (4096 windows). 512 threads = 8 waves.
// LDS: xw 64x260 (66560B) + 4 tiles 64x32 (32768B) + sc 64x68 (17408B) = 116736B
__global__ __launch_bounds__(512, 2) void swin_attn(
    const float* __restrict__ x, const float* __restrict__ qkv_w,
    const float* __restrict__ qkv_b, const float* __restrict__ proj_w,
    const float* __restrict__ proj_b, const float* __restrict__ rpb,
    const float* __restrict__ ln1g, const float* __restrict__ ln1b,
    float* __restrict__ outw)
{
  __shared__ float xw[64 * 260];
  __shared__ float qh[64 * 32];
  __shared__ float kh[64 * 32];
  __shared__ float vh[64 * 32];
  __shared__ float oh[64 * 32];
  __shared__ float sc[64 * 68];

  const int t = threadIdx.x;
  const int wv = t >> 6, lane = t & 63;
  const int blk = blockIdx.x;
  const int b = blk >> 8, w = blk & 255;
  const int wi = w >> 4, wj = w & 15;

  // ---- Phase 0: gather 64 rows (shift+window mapping) + LN1, wave-per-row ----
  #pragma unroll
  for (int i = 0; i < 8; ++i) {
    const int r = wv * 8 + i;
    const int ui = (wi * 8 + (r >> 3) + SHIFT_N) & 127;
    const int uj = (wj * 8 + (r & 7) + SHIFT_N) & 127;
    const long row = ((long)b << 14) + (ui << 7) + uj;
    const float4 v = *(const float4*)(x + row * 256 + lane * 4);
    float s = v.x + v.y + v.z + v.w;
    #pragma unroll
    for (int o = 32; o; o >>= 1) s += __shfl_xor(s, o);
    const float mu = s * (1.f / 256.f);
    const float d0 = v.x - mu, d1 = v.y - mu, d2 = v.z - mu, d3 = v.w - mu;
    float q = d0 * d0 + d1 * d1 + d2 * d2 + d3 * d3;
    #pragma unroll
    for (int o = 32; o; o >>= 1) q += __shfl_xor(q, o);
    const float rs = rsq_acc(q * (1.f / 256.f) + 1e-5f);
    const float4 g4 = *(const float4*)(ln1g + lane * 4);
    const float4 b4 = *(const float4*)(ln1b + lane * 4);
    float* p = xw + r * 260 + lane * 4;
    p[0] = d0 * rs * g4.x + b4.x;
    p[1] = d1 * rs * g4.y + b4.y;
    p[2] = d2 * rs * g4.z + b4.z;
    p[3] = d3 * rs * g4.w + b4.w;
  }
  __syncthreads();

  const int r = t >> 3, sub = t & 7;
  const int ni = r >> 3, nj = r & 7;

  float fin[32];
  #pragma unroll
  for (int j = 0; j < 32; ++j) fin[j] = 0.f;

  for (int h = 0; h < 8; ++h) {
    // ---- (a) qkv head slice: row r, cols 4*sub..4*sub+3 of q,k,v ----
    {
      float4 qa = {0, 0, 0, 0}, ka = {0, 0, 0, 0}, va = {0, 0, 0, 0};
      const float* xr = xw + r * 260;
      const int cq = h * 32 + sub * 4;
      const float* wqp = qkv_w + cq;
      #pragma unroll 4
      for (int kk = 0; kk < 256; ++kk) {
        const float xv = xr[kk];
        const float4 aq = *(const float4*)(wqp + kk * 768);
        const float4 ak = *(const float4*)(wqp + kk * 768 + 256);
        const float4 av = *(const float4*)(wqp + kk * 768 + 512);
        qa.x += xv * aq.x; qa.y += xv * aq.y; qa.z += xv * aq.z; qa.w += xv * aq.w;
        ka.x += xv * ak.x; ka.y += xv * ak.y; ka.z += xv * ak.z; ka.w += xv * ak.w;
        va.x += xv * av.x; va.y += xv * av.y; va.z += xv * av.z; va.w += xv * av.w;
      }
      const float4 bq = *(const float4*)(qkv_b + cq);
      const float4 bk = *(const float4*)(qkv_b + 256 + cq);
      const float4 bv = *(const float4*)(qkv_b + 512 + cq);
      const float SC = 0.17677669529663687f;  // 32^-0.5
      float4 qs; qs.x = (qa.x + bq.x) * SC; qs.y = (qa.y + bq.y) * SC;
      qs.z = (qa.z + bq.z) * SC; qs.w = (qa.w + bq.w) * SC;
      *(float4*)tptr(qh, r, sub) = qs;
      float4 ks; ks.x = ka.x + bk.x; ks.y = ka.y + bk.y; ks.z = ka.z + bk.z; ks.w = ka.w + bk.w;
      *(float4*)tptr(kh, r, sub) = ks;
      float4 vs; vs.x = va.x + bv.x; vs.y = va.y + bv.y; vs.z = va.z + bv.z; vs.w = va.w + bv.w;
      *(float4*)tptr(vh, r, sub) = vs;
    }
    __syncthreads();

    // ---- (b) scores + rel-pos bias + softmax. Thread: row r, m = sub+8*j ----
    {
      float acc[8] = {0, 0, 0, 0, 0, 0, 0, 0};
      #pragma unroll
      for (int g = 0; g < 8; ++g) {
        const float4 q4 = *(const float4*)tptrc(qh, r, g);
        #pragma unroll
        for (int j = 0; j < 8; ++j) {
          const int m = sub + 8 * j;
          const float4 k4 = *(const float4*)tptrc(kh, m, g);
          acc[j] += q4.x * k4.x + q4.y * k4.y + q4.z * k4.z + q4.w * k4.w;
        }
      }
      float mx = -3e38f;
      #pragma unroll
      for (int j = 0; j < 8; ++j) {
        const int m = sub + 8 * j;
        const int idx = (ni - (m >> 3) + 7) * 15 + (nj - (m & 7) + 7);
        acc[j] += rpb[idx * 8 + h];
        mx = fmaxf(mx, acc[j]);
      }
      #pragma unroll
      for (int o = 1; o < 8; o <<= 1) mx = fmaxf(mx, __shfl_xor(mx, o));
      float sum = 0.f;
      float pr[8];
      #pragma unroll
      for (int j = 0; j < 8; ++j) { pr[j] = __expf(acc[j] - mx); sum += pr[j]; }
      #pragma unroll
      for (int o = 1; o < 8; o <<= 1) sum += __shfl_xor(sum, o);
      const float inv = 1.f / sum;
      #pragma unroll
      for (int j = 0; j < 8; ++j) sc[r * 68 + sub + 8 * j] = pr[j] * inv;
    }
    __syncthreads();

    // ---- (d) PV: oh[r][4sub..] = sum_m P[r][m] * vh[m][...] ----
    {
      float4 oa = {0, 0, 0, 0};
      const float* scr = sc + r * 68;
      #pragma unroll 8
      for (int m = 0; m < 64; ++m) {
        const float p = scr[m];
        const float4 v4 = *(const float4*)tptrc(vh, m, sub);
        oa.x += p * v4.x; oa.y += p * v4.y; oa.z += p * v4.z; oa.w += p * v4.w;
      }
      *(float4*)tptr(oh, r, sub) = oa;
    }
    __syncthreads();

    // ---- (e) proj accumulate: fin[j] += oh[r][kk] * proj_w[h*32+kk][sub*32+j] ----
    {
      const float* pw = proj_w + (h * 32) * 256 + sub * 32;
      #pragma unroll
      for (int g = 0; g < 8; ++g) {
        const float4 o4 = *(const float4*)tptrc(oh, r, g);
        const float ov[4] = {o4.x, o4.y, o4.z, o4.w};
        #pragma unroll
        for (int e = 0; e < 4; ++e) {
          const float4* wr = (const float4*)(pw + (g * 4 + e) * 256);
          #pragma unroll
          for (int j4 = 0; j4 < 8; ++j4) {
            const float4 w4 = wr[j4];
            fin[j4 * 4 + 0] += ov[e] * w4.x;
            fin[j4 * 4 + 1] += ov[e] * w4.y;
            fin[j4 * 4 + 2] += ov[e] * w4.z;
            fin[j4 * 4 + 3] += ov[e] * w4.w;
          }
        }
      }
    }
    __syncthreads();
  }

  // ---- write back (inverse shift == same source row) ----
  {
    const int ui = (wi * 8 + ni + SHIFT_N) & 127;
    const int uj = (wj * 8 + nj + SHIFT_N) & 127;
    const long row = ((long)b << 14) + (ui << 7) + uj;
    float* op = outw + row * 256 + sub * 32;
    #pragma unroll
    for (int j4 = 0; j4 < 8; ++j4) {
      const float4 pbv = *(const float4*)(proj_b + sub * 32 + j4 * 4);
      float4 o;
      o.x = fin[j4 * 4 + 0] + pbv.x;
      o.y = fin[j4 * 4 + 1] + pbv.y;
      o.z = fin[j4 * 4 + 2] + pbv.z;
      o.w = fin[j4 * 4 + 3] + pbv.w;
      *(float4*)(op + j4 * 4) = o;
    }
  }
}

// One block per 64 rows. LN2 -> GEMM1(4 chunks)+GELU -> GEMM2 -> x+out+mlp.
// LDS: h2 64x260 + hid 64x260 = 133120B
__global__ __launch_bounds__(512, 2) void swin_mlp(
    const float* __restrict__ x, const float* __restrict__ outw,
    const float* __restrict__ ln2g, const float* __restrict__ ln2b,
    const float* __restrict__ w1, const float* __restrict__ b1,
    const float* __restrict__ w2, const float* __restrict__ b2,
    float* __restrict__ y)
{
  __shared__ float h2[64 * 260];
  __shared__ float hid[64 * 260];
  const int t = threadIdx.x;
  const int wv = t >> 6, lane = t & 63;
  const long base = (long)blockIdx.x << 6;

  #pragma unroll
  for (int i = 0; i < 8; ++i) {
    const int r = wv * 8 + i;
    const long row = base + r;
    const float4 v = *(const float4*)(outw + row * 256 + lane * 4);
    float s = v.x + v.y + v.z + v.w;
    #pragma unroll
    for (int o = 32; o; o >>= 1) s += __shfl_xor(s, o);
    const float mu = s * (1.f / 256.f);
    const float d0 = v.x - mu, d1 = v.y - mu, d2 = v.z - mu, d3 = v.w - mu;
    float q = d0 * d0 + d1 * d1 + d2 * d2 + d3 * d3;
    #pragma unroll
    for (int o = 32; o; o >>= 1) q += __shfl_xor(q, o);
    const float rs = rsq_acc(q * (1.f / 256.f) + 1e-5f);
    const float4 g4 = *(const float4*)(ln2g + lane * 4);
    const float4 b4 = *(const float4*)(ln2b + lane * 4);
    float* p = h2 + r * 260 + lane * 4;
    p[0] = d0 * rs * g4.x + b4.x;
    p[1] = d1 * rs * g4.y + b4.y;
    p[2] = d2 * rs * g4.z + b4.z;
    p[3] = d3 * rs * g4.w + b4.w;
  }
  __syncthreads();

  const int r = t >> 3, sub = t & 7;
  const int c0 = sub * 32;

  float o2[32];
  #pragma unroll
  for (int j = 0; j < 32; ++j) o2[j] = 0.f;

  for (int ch = 0; ch < 4; ++ch) {
    const int cc = ch << 8;
    float a1[32];
    #pragma unroll
    for (int j4 = 0; j4 < 8; ++j4) {
      const float4 bb = *(const float4*)(b1 + cc + c0 + j4 * 4);
      a1[j4 * 4 + 0] = bb.x; a1[j4 * 4 + 1] = bb.y;
      a1[j4 * 4 + 2] = bb.z; a1[j4 * 4 + 3] = bb.w;
    }
    const float* hr = h2 + r * 260;
    #pragma unroll 4
    for (int kk = 0; kk < 256; ++kk) {
      const float hv = hr[kk];
      const float4* wr = (const float4*)(w1 + kk * 1024 + cc + c0);
      #pragma unroll
      for (int j4 = 0; j4 < 8; ++j4) {
        const float4 w4 = wr[j4];
        a1[j4 * 4 + 0] += hv * w4.x;
        a1[j4 * 4 + 1] += hv * w4.y;
        a1[j4 * 4 + 2] += hv * w4.z;
        a1[j4 * 4 + 3] += hv * w4.w;
      }
    }
    float* hw = hid + r * 260 + c0;
    #pragma unroll
    for (int j = 0; j < 32; ++j) {
      const float v = a1[j];
      hw[j] = 0.5f * v * (1.f + erff(v * 0.70710678118654752f));  // exact gelu
    }
    __syncthreads();
    const float* hr2 = hid + r * 260;
    #pragma unroll 4
    for (int kk = 0; kk < 256; ++kk) {
      const float hv = hr2[kk];
      const float4* wr = (const float4*)(w2 + (cc + kk) * 256 + c0);
      #pragma unroll
      for (int j4 = 0; j4 < 8; ++j4) {
        const float4 w4 = wr[j4];
        o2[j4 * 4 + 0] += hv * w4.x;
        o2[j4 * 4 + 1] += hv * w4.y;
        o2[j4 * 4 + 2] += hv * w4.z;
        o2[j4 * 4 + 3] += hv * w4.w;
      }
    }
    __syncthreads();
  }

  const long row = base + r;
  #pragma unroll
  for (int j4 = 0; j4 < 8; ++j4) {
    const float4 xv = *(const float4*)(x + row * 256 + c0 + j4 * 4);
    const float4 ov = *(const float4*)(outw + row * 256 + c0 + j4 * 4);
    const float4 bv = *(const float4*)(b2 + c0 + j4 * 4);
    float4 res;
    res.x = xv.x + ov.x + o2[j4 * 4 + 0] + bv.x;
    res.y = xv.y + ov.y + o2[j4 * 4 + 1] + bv.y;
    res.z = xv.z + ov.z + o2[j4 * 4 + 2] + bv.z;
    res.w = xv.w + ov.w + o2[j4 * 4 + 3] + bv.w;
    *(float4*)(y + row * 256 + c0 + j4 * 4) = res;
  }
}

extern "C" void kernel_launch(void* const* d_in, const int* in_sizes, int n_in,
                              void* d_out, int out_size, void* d_ws, size_t ws_size,
                              hipStream_t stream) {
  (void)in_sizes; (void)n_in; (void)out_size; (void)ws_size;
  const float* x      = (const float*)d_in[0];
  const float* qkv_w  = (const float*)d_in[1];
  const float* qkv_b  = (const float*)d_in[2];
  const float* proj_w = (const float*)d_in[3];
  const float* proj_b = (const float*)d_in[4];
  const float* rpb    = (const float*)d_in[5];
  const float* ln1g   = (const float*)d_in[6];
  const float* ln1b   = (const float*)d_in[7];
  const float* ln2g   = (const float*)d_in[8];
  const float* ln2b   = (const float*)d_in[9];
  const float* w1     = (const float*)d_in[10];
  const float* b1     = (const float*)d_in[11];
  const float* w2     = (const float*)d_in[12];
  const float* b2     = (const float*)d_in[13];
  float* y    = (float*)d_out;
  float* outw = (float*)d_ws;  // attention-branch output, (B*L, 256) fp32 = 268MB

  hipLaunchKernelGGL(swin_attn, dim3(4096), dim3(512), 0, stream,
                     x, qkv_w, qkv_b, proj_w, proj_b, rpb, ln1g, ln1b, outw);
  hipLaunchKernelGGL(swin_mlp, dim3(4096), dim3(512), 0, stream,
                     x, outw, ln2g, ln2b, w1, b1, w2, b2, y);
}

// Round 3
// 2632.909 us; speedup vs baseline: 34.4576x; 34.4576x over previous
//
#include <hip/hip_runtime.h>
#include <math.h>

typedef short bfrag __attribute__((ext_vector_type(8)));   // 8 bf16 (4 VGPR)
typedef float ffrag __attribute__((ext_vector_type(4)));   // 4 f32 accum

#define MFMA16(a, b, c) __builtin_amdgcn_mfma_f32_16x16x32_bf16((a), (b), (c), 0, 0, 0)

__device__ __forceinline__ unsigned bf16b(float f) {   // fp32 -> bf16 bits, RNE
  unsigned u = __float_as_uint(f);
  return (u + 0x7FFFu + ((u >> 16) & 1u)) >> 16;
}
__device__ __forceinline__ unsigned pk2(float lo, float hi) {
  return bf16b(lo) | (bf16b(hi) << 16);
}

// Byte offset into a [*][C] bf16 LDS tile, XOR-swizzled per 16B slot:
// phys_slot = (col/8) ^ (row&7). Row stride C*2 bytes (C in {64,128,256}).
// All writers and readers go through this one function.
__device__ __forceinline__ int swz(int row, int col, int C) {
  return row * (C * 2) + ((((col >> 3) ^ (row & 7)) << 4) + ((col & 7) << 1));
}

// MFMA operand fragment load. For both A and B operands the lane mapping is
// outer = base + (lane&15), k = k0 + (lane>>4)*8 .. +8  (16x16x32 bf16).
__device__ __forceinline__ bfrag ldfrag(const char* lds, int outer, int k0, int C) {
  const int l = threadIdx.x & 63;
  return *(const bfrag*)(lds + swz(outer + (l & 15), k0 + ((l >> 4) << 3), C));
}

// Transpose-stage W (global fp32, row-major [K'][ldw], rows K0.., cols C0..C0+NC)
// into LDS tile [NC][NK] bf16 (outer = col of W, inner = k), swizzled. 512 thr.
__device__ __forceinline__ void stage_wt(char* dst, const float* __restrict__ W,
                                         int ldw, int C0, int K0, int NC, int NK) {
  const int cpt = NC >> 2;
  const int items = cpt * (NK >> 1);
  for (int idx = threadIdx.x; idx < items; idx += 512) {
    const int c = (idx % cpt) << 2;
    const int k = (idx / cpt) << 1;
    const float4 w0 = *(const float4*)(W + (long)(K0 + k) * ldw + C0 + c);
    const float4 w1 = *(const float4*)(W + (long)(K0 + k + 1) * ldw + C0 + c);
    *(unsigned*)(dst + swz(c + 0, k, NK)) = pk2(w0.x, w1.x);
    *(unsigned*)(dst + swz(c + 1, k, NK)) = pk2(w0.y, w1.y);
    *(unsigned*)(dst + swz(c + 2, k, NK)) = pk2(w0.z, w1.z);
    *(unsigned*)(dst + swz(c + 3, k, NK)) = pk2(w0.w, w1.w);
  }
}

// Wave-per-row LayerNorm of one 256-col fp32 row -> bf16 LDS tile row r.
__device__ __forceinline__ void ln_row_to_lds(char* dst, const float* __restrict__ src,
                                              const float* __restrict__ g,
                                              const float* __restrict__ bb, int r) {
  const int lane = threadIdx.x & 63;
  const float4 v = *(const float4*)(src + lane * 4);
  float s = v.x + v.y + v.z + v.w;
  #pragma unroll
  for (int o = 32; o; o >>= 1) s += __shfl_xor(s, o);
  const float mu = s * (1.f / 256.f);
  const float d0 = v.x - mu, d1 = v.y - mu, d2 = v.z - mu, d3 = v.w - mu;
  float q = d0 * d0 + d1 * d1 + d2 * d2 + d3 * d3;
  #pragma unroll
  for (int o = 32; o; o >>= 1) q += __shfl_xor(q, o);
  float rs = rsqrtf(q * (1.f / 256.f) + 1e-5f);
  rs = rs * (1.5f - 0.5f * (q * (1.f / 256.f) + 1e-5f) * rs * rs);  // Newton
  const float4 g4 = *(const float4*)(g + lane * 4);
  const float4 b4 = *(const float4*)(bb + lane * 4);
  const int c = lane * 4;
  *(unsigned*)(dst + swz(r, c, 256)) = pk2(d0 * rs * g4.x + b4.x, d1 * rs * g4.y + b4.y);
  *(unsigned*)(dst + swz(r, c + 2, 256)) = pk2(d2 * rs * g4.z + b4.z, d3 * rs * g4.w + b4.w);
}

// ---------------- attention kernel: one block per 8x8 window ----------------
// LDS 147456B: XW[64][256] (LN'd x, later O) | WS 16KB (W-stage, later P0/P1)
//            | QL[64][256] | KL[64][256] | VT[256][64]   (all bf16, swizzled)
__global__ __launch_bounds__(512) void swin_attn(
    const float* __restrict__ x, const float* __restrict__ qkv_w,
    const float* __restrict__ qkv_b, const float* __restrict__ proj_w,
    const float* __restrict__ proj_b, const float* __restrict__ rpb,
    const float* __restrict__ ln1g, const float* __restrict__ ln1b,
    float* __restrict__ outw)
{
  __shared__ __align__(16) char smem[147456];
  char* XW = smem;
  char* WS = smem + 32768;
  char* QL = smem + 49152;
  char* KL = smem + 81920;
  char* VT = smem + 114688;

  const int t = threadIdx.x;
  const int wv = t >> 6, l = t & 63;
  const int blk = blockIdx.x;
  const int b = blk >> 8, w = blk & 255;
  const int wi = w >> 4, wj = w & 15;

  // Phase 0: gather (roll -4) + LN1 -> XW
  #pragma unroll
  for (int i = 0; i < 8; ++i) {
    const int r = wv * 8 + i;
    const int ui = (wi * 8 + (r >> 3) + 4) & 127;
    const int uj = (wj * 8 + (r & 7) + 4) & 127;
    const long row = ((long)b << 14) + (ui << 7) + uj;
    ln_row_to_lds(XW, x + row * 256, ln1g, ln1b, r);
  }
  __syncthreads();

  const int MB = (wv >> 2) << 4;  // col-tile within a 32-col chunk
  const int NB = (wv & 3) << 4;   // row-tile
  const float SC = 0.17677669529663687f;

  // Phase 1: qkv GEMM in 24 chunks of 32 output cols, K=256
  for (int ch = 0; ch < 24; ++ch) {
    stage_wt(WS, qkv_w, 768, ch * 32, 0, 32, 256);
    __syncthreads();
    ffrag acc = {0.f, 0.f, 0.f, 0.f};
    #pragma unroll
    for (int ks = 0; ks < 8; ++ks) {
      const bfrag a = ldfrag(WS, MB, ks * 32, 256);
      const bfrag bb = ldfrag(XW, NB, ks * 32, 256);
      acc = MFMA16(a, bb, acc);
    }
    // D[m=col][n=row]: lane holds 4 consecutive cols (regs) of row NB+(l&15)
    const int r = NB + (l & 15);
    const int cg = ch * 32 + MB + ((l >> 4) << 2);
    const float4 b4 = *(const float4*)(qkv_b + cg);
    float v0 = acc.x + b4.x, v1 = acc.y + b4.y, v2 = acc.z + b4.z, v3 = acc.w + b4.w;
    if (cg < 256) {          // Q (pre-scaled)
      v0 *= SC; v1 *= SC; v2 *= SC; v3 *= SC;
      *(unsigned*)(QL + swz(r, cg, 256)) = pk2(v0, v1);
      *(unsigned*)(QL + swz(r, cg + 2, 256)) = pk2(v2, v3);
    } else if (cg < 512) {   // K
      const int c = cg - 256;
      *(unsigned*)(KL + swz(r, c, 256)) = pk2(v0, v1);
      *(unsigned*)(KL + swz(r, c + 2, 256)) = pk2(v2, v3);
    } else {                 // V, stored transposed [vcol][row]
      const int c = cg - 512;
      *(unsigned short*)(VT + swz(c + 0, r, 64)) = (unsigned short)bf16b(v0);
      *(unsigned short*)(VT + swz(c + 1, r, 64)) = (unsigned short)bf16b(v1);
      *(unsigned short*)(VT + swz(c + 2, r, 64)) = (unsigned short)bf16b(v2);
      *(unsigned short*)(VT + swz(c + 3, r, 64)) = (unsigned short)bf16b(v3);
    }
    __syncthreads();
  }

  // Phase 2: attention, 2 heads in parallel (waves 0-3 / 4-7)
  const int w4 = wv & 3;
  const int half = wv >> 2;
  for (int hp = 0; hp < 4; ++hp) {
    const int h = hp * 2 + half;
    char* PB = WS + half * 8192;   // [64][64] bf16 P-buffer per head
    const int hk = h * 32;

    // S = Q K^T (direct: A=Q rows, B=K rows), one 16x16x32 MFMA per tile
    const bfrag aq = ldfrag(QL, w4 * 16, hk, 256);
    ffrag s[4];
    #pragma unroll
    for (int nt = 0; nt < 4; ++nt) {
      const bfrag bk = ldfrag(KL, nt * 16, hk, 256);
      ffrag z = {0.f, 0.f, 0.f, 0.f};
      s[nt] = MFMA16(aq, bk, z);
    }
    // bias + in-register softmax; row = w4*16+(l>>4)*4+reg, col = nt*16+(l&15)
    const int colb = l & 15;
    const int rbase = w4 * 16 + ((l >> 4) << 2);
    float pr[4][4], mx[4], sm[4];
    #pragma unroll
    for (int reg = 0; reg < 4; ++reg) mx[reg] = -3e38f;
    #pragma unroll
    for (int nt = 0; nt < 4; ++nt) {
      #pragma unroll
      for (int reg = 0; reg < 4; ++reg) {
        const int rr = rbase + reg, cc = nt * 16 + colb;
        const int idx = ((rr >> 3) - (cc >> 3) + 7) * 15 + ((rr & 7) - (cc & 7) + 7);
        pr[nt][reg] = s[nt][reg] + rpb[idx * 8 + h];
        mx[reg] = fmaxf(mx[reg], pr[nt][reg]);
      }
    }
    #pragma unroll
    for (int reg = 0; reg < 4; ++reg) {
      #pragma unroll
      for (int o = 1; o < 16; o <<= 1) mx[reg] = fmaxf(mx[reg], __shfl_xor(mx[reg], o));
      sm[reg] = 0.f;
    }
    #pragma unroll
    for (int nt = 0; nt < 4; ++nt)
      #pragma unroll
      for (int reg = 0; reg < 4; ++reg) {
        pr[nt][reg] = __expf(pr[nt][reg] - mx[reg]);
        sm[reg] += pr[nt][reg];
      }
    #pragma unroll
    for (int reg = 0; reg < 4; ++reg) {
      #pragma unroll
      for (int o = 1; o < 16; o <<= 1) sm[reg] += __shfl_xor(sm[reg], o);
      sm[reg] = 1.f / sm[reg];
    }
    #pragma unroll
    for (int nt = 0; nt < 4; ++nt)
      #pragma unroll
      for (int reg = 0; reg < 4; ++reg)
        *(unsigned short*)(PB + swz(rbase + reg, nt * 16 + colb, 64)) =
            (unsigned short)bf16b(pr[nt][reg] * sm[reg]);
    __syncthreads();

    // PV: A = P [qrow][k=64], B^T = VT [vd][k]; D[m=qrow][n=vd]
    ffrag o0 = {0.f, 0.f, 0.f, 0.f}, o1 = {0.f, 0.f, 0.f, 0.f};
    #pragma unroll
    for (int ks = 0; ks < 2; ++ks) {
      const bfrag ap = ldfrag(PB, w4 * 16, ks * 32, 64);
      const bfrag bv0 = ldfrag(VT, hk, ks * 32, 64);
      const bfrag bv1 = ldfrag(VT, hk + 16, ks * 32, 64);
      o0 = MFMA16(ap, bv0, o0);
      o1 = MFMA16(ap, bv1, o1);
    }
    // O -> XW region [row][256]; lane holds rows rbase+reg at one vd col
    #pragma unroll
    for (int reg = 0; reg < 4; ++reg) {
      *(unsigned short*)(XW + swz(rbase + reg, hk + colb, 256)) = (unsigned short)bf16b(o0[reg]);
      *(unsigned short*)(XW + swz(rbase + reg, hk + 16 + colb, 256)) = (unsigned short)bf16b(o1[reg]);
    }
    __syncthreads();
  }

  // Phase 3: proj in 8 chunks of 32 cols; scatter (roll +4) with proj bias
  for (int ch = 0; ch < 8; ++ch) {
    stage_wt(WS, proj_w, 256, ch * 32, 0, 32, 256);
    __syncthreads();
    ffrag acc = {0.f, 0.f, 0.f, 0.f};
    #pragma unroll
    for (int ks = 0; ks < 8; ++ks) {
      const bfrag a = ldfrag(WS, MB, ks * 32, 256);
      const bfrag bo = ldfrag(XW, NB, ks * 32, 256);
      acc = MFMA16(a, bo, acc);
    }
    const int r = NB + (l & 15);
    const int c0 = ch * 32 + MB + ((l >> 4) << 2);
    const float4 pb4 = *(const float4*)(proj_b + c0);
    const int ui = (wi * 8 + (r >> 3) + 4) & 127;
    const int uj = (wj * 8 + (r & 7) + 4) & 127;
    const long row = ((long)b << 14) + (ui << 7) + uj;
    float4 o4;
    o4.x = acc.x + pb4.x; o4.y = acc.y + pb4.y;
    o4.z = acc.z + pb4.z; o4.w = acc.w + pb4.w;
    *(float4*)(outw + row * 256 + c0) = o4;
    __syncthreads();
  }
}

// ---------------- MLP kernel: one block per 64 rows ----------------
// LDS 114688B: H2[64][256] | WS 64KB (Wt1 [128][256] / Wt2 [256][128]) | HD[64][128]
__global__ __launch_bounds__(512) void swin_mlp(
    const float* __restrict__ x, const float* __restrict__ outw,
    const float* __restrict__ ln2g, const float* __restrict__ ln2b,
    const float* __restrict__ w1, const float* __restrict__ b1,
    const float* __restrict__ w2, const float* __restrict__ b2,
    float* __restrict__ y)
{
  __shared__ __align__(16) char smem[114688];
  char* H2 = smem;
  char* WS = smem + 32768;
  char* HD = smem + 98304;
  const int t = threadIdx.x, wv = t >> 6, l = t & 63;
  const long base = (long)blockIdx.x << 6;

  #pragma unroll
  for (int i = 0; i < 8; ++i) {
    const int r = wv * 8 + i;
    ln_row_to_lds(H2, outw + (base + r) * 256, ln2g, ln2b, r);
  }
  __syncthreads();

  ffrag acc2[2][4];
  {
    ffrag z = {0.f, 0.f, 0.f, 0.f};
    #pragma unroll
    for (int mt = 0; mt < 2; ++mt)
      #pragma unroll
      for (int nt = 0; nt < 4; ++nt) acc2[mt][nt] = z;
  }

  for (int ch = 0; ch < 8; ++ch) {
    // GEMM1 chunk: 128 hidden cols
    stage_wt(WS, w1, 1024, ch * 128, 0, 128, 256);
    __syncthreads();
    ffrag a1[4];
    {
      ffrag z = {0.f, 0.f, 0.f, 0.f};
      #pragma unroll
      for (int nt = 0; nt < 4; ++nt) a1[nt] = z;
    }
    #pragma unroll
    for (int ks = 0; ks < 8; ++ks) {
      const bfrag a = ldfrag(WS, wv * 16, ks * 32, 256);
      #pragma unroll
      for (int nt = 0; nt < 4; ++nt) {
        const bfrag bb = ldfrag(H2, nt * 16, ks * 32, 256);
        a1[nt] = MFMA16(a, bb, a1[nt]);
      }
    }
    __syncthreads();  // all waves done reading Wt1 before restage

    // bias + exact GELU -> HD (bf16)
    const int c0 = wv * 16 + ((l >> 4) << 2);
    const float4 b14 = *(const float4*)(b1 + ch * 128 + c0);
    #pragma unroll
    for (int nt = 0; nt < 4; ++nt) {
      const int rr = nt * 16 + (l & 15);
      const float u0 = a1[nt][0] + b14.x, u1 = a1[nt][1] + b14.y;
      const float u2 = a1[nt][2] + b14.z, u3 = a1[nt][3] + b14.w;
      const float g0 = 0.5f * u0 * (1.f + erff(u0 * 0.70710678118654752f));
      const float g1 = 0.5f * u1 * (1.f + erff(u1 * 0.70710678118654752f));
      const float g2 = 0.5f * u2 * (1.f + erff(u2 * 0.70710678118654752f));
      const float g3 = 0.5f * u3 * (1.f + erff(u3 * 0.70710678118654752f));
      *(unsigned*)(HD + swz(rr, c0, 128)) = pk2(g0, g1);
      *(unsigned*)(HD + swz(rr, c0 + 2, 128)) = pk2(g2, g3);
    }
    stage_wt(WS, w2, 256, 0, ch * 128, 256, 128);
    __syncthreads();

    // GEMM2 accumulate over this 128-k chunk
    #pragma unroll
    for (int ks = 0; ks < 4; ++ks) {
      const bfrag am0 = ldfrag(WS, (wv * 2) * 16, ks * 32, 128);
      const bfrag am1 = ldfrag(WS, (wv * 2 + 1) * 16, ks * 32, 128);
      #pragma unroll
      for (int nt = 0; nt < 4; ++nt) {
        const bfrag bb = ldfrag(HD, nt * 16, ks * 32, 128);
        acc2[0][nt] = MFMA16(am0, bb, acc2[0][nt]);
        acc2[1][nt] = MFMA16(am1, bb, acc2[1][nt]);
      }
    }
    __syncthreads();  // WS/HD reads done before next chunk overwrites
  }

  // epilogue: y = x + outw + mlp
  #pragma unroll
  for (int mt = 0; mt < 2; ++mt) {
    const int c0 = (wv * 2 + mt) * 16 + ((l >> 4) << 2);
    const float4 b24 = *(const float4*)(b2 + c0);
    #pragma unroll
    for (int nt = 0; nt < 4; ++nt) {
      const long row = base + nt * 16 + (l & 15);
      const float4 xv = *(const float4*)(x + row * 256 + c0);
      const float4 ov = *(const float4*)(outw + row * 256 + c0);
      float4 res;
      res.x = xv.x + ov.x + acc2[mt][nt][0] + b24.x;
      res.y = xv.y + ov.y + acc2[mt][nt][1] + b24.y;
      res.z = xv.z + ov.z + acc2[mt][nt][2] + b24.z;
      res.w = xv.w + ov.w + acc2[mt][nt][3] + b24.w;
      *(float4*)(y + row * 256 + c0) = res;
    }
  }
}

extern "C" void kernel_launch(void* const* d_in, const int* in_sizes, int n_in,
                              void* d_out, int out_size, void* d_ws, size_t ws_size,
                              hipStream_t stream) {
  (void)in_sizes; (void)n_in; (void)out_size; (void)ws_size;
  const float* x      = (const float*)d_in[0];
  const float* qkv_w  = (const float*)d_in[1];
  const float* qkv_b  = (const float*)d_in[2];
  const float* proj_w = (const float*)d_in[3];
  const float* proj_b = (const float*)d_in[4];
  const float* rpb    = (const float*)d_in[5];
  const float* ln1g   = (const float*)d_in[6];
  const float* ln1b   = (const float*)d_in[7];
  const float* ln2g   = (const float*)d_in[8];
  const float* ln2b   = (const float*)d_in[9];
  const float* w1     = (const float*)d_in[10];
  const float* b1     = (const float*)d_in[11];
  const float* w2     = (const float*)d_in[12];
  const float* b2     = (const float*)d_in[13];
  float* y    = (float*)d_out;
  float* outw = (float*)d_ws;  // attention-branch output, (B*L, 256) fp32

  hipLaunchKernelGGL(swin_attn, dim3(4096), dim3(512), 0, stream,
                     x, qkv_w, qkv_b, proj_w, proj_b, rpb, ln1g, ln1b, outw);
  hipLaunchKernelGGL(swin_mlp, dim3(4096), dim3(512), 0, stream,
                     x, outw, ln2g, ln2b, w1, b1, w2, b2, y);
}

// Round 4
// 1425.902 us; speedup vs baseline: 63.6255x; 1.8465x over previous
//
#include <hip/hip_runtime.h>
#include <math.h>

typedef short bfrag __attribute__((ext_vector_type(8)));   // 8 bf16 (4 VGPR)
typedef float ffrag __attribute__((ext_vector_type(4)));   // 4 f32 accum

#define MFMA16(a, b, c) __builtin_amdgcn_mfma_f32_16x16x32_bf16((a), (b), (c), 0, 0, 0)

// Pre-transposed bf16 weights, converted once per launch by conv_w.
// Layout: [outcol][k] row-major. qkv @0 (768x256), proj @196608 (256x256),
// w1 @262144 (1024x256), w2 @524288 (256x1024). Total 786432 shorts = 1.5MB.
__device__ __align__(16) unsigned short g_wt[786432];

__device__ __forceinline__ unsigned bf16b(float f) {   // fp32 -> bf16 bits, RNE
  unsigned u = __float_as_uint(f);
  return (u + 0x7FFFu + ((u >> 16) & 1u)) >> 16;
}
__device__ __forceinline__ unsigned pk2(float lo, float hi) {
  return bf16b(lo) | (bf16b(hi) << 16);
}

__global__ void conv_w(const float* __restrict__ qkv_w, const float* __restrict__ proj_w,
                       const float* __restrict__ w1, const float* __restrict__ w2) {
  const int idx = blockIdx.x * 256 + threadIdx.x;   // 393216 (c,k2) pairs
  const float* src; int c, k2, C, K, ofs;
  if (idx < 98304)       { src = qkv_w;  C = 768;  K = 256;  c = idx % 768;  k2 = idx / 768;  ofs = 0; }
  else if (idx < 131072) { int i = idx - 98304;  src = proj_w; C = 256;  K = 256;  c = i % 256;  k2 = i / 256;  ofs = 196608; }
  else if (idx < 262144) { int i = idx - 131072; src = w1;     C = 1024; K = 256;  c = i % 1024; k2 = i / 1024; ofs = 262144; }
  else                   { int i = idx - 262144; src = w2;     C = 256;  K = 1024; c = i % 256;  k2 = i / 256;  ofs = 524288; }
  const float lo = src[(2 * k2) * C + c];
  const float hi = src[(2 * k2 + 1) * C + c];
  *(unsigned*)&g_wt[ofs + c * K + 2 * k2] = pk2(lo, hi);
}

// Byte offset into a [*][C] bf16 LDS tile, XOR-swizzled per 16B slot:
// phys_slot = (col/8) ^ (row&7). Row stride C*2 bytes (C in {64,128,256}).
__device__ __forceinline__ int swz(int row, int col, int C) {
  return row * (C * 2) + ((((col >> 3) ^ (row & 7)) << 4) + ((col & 7) << 1));
}

// MFMA operand fragment load: outer = base + (lane&15), k = k0 + (lane>>4)*8.
__device__ __forceinline__ bfrag ldfrag(const char* lds, int outer, int k0, int C) {
  const int l = threadIdx.x & 63;
  return *(const bfrag*)(lds + swz(outer + (l & 15), k0 + ((l >> 4) << 3), C));
}

// Stage a bf16 W^T tile global->LDS via global_load_lds (linear LDS dest,
// inverse-swizzled global source; rule #21). DSTROWB = LDS row bytes (pow2).
template <int DSTROWB>
__device__ __forceinline__ void glds_stage(char* lds, const unsigned short* src,
                                           int srcRowShorts, int bytes) {
  const int wv = threadIdx.x >> 6, l = threadIdx.x & 63;
  for (int base = wv * 1024; base < bytes; base += 8192) {
    const int off = base + l * 16;
    const int row = off / DSTROWB;
    const int slot = (off % DSTROWB) >> 4;
    const int sslot = slot ^ (row & 7);
    const unsigned short* g = src + row * srcRowShorts + sslot * 8;
    __builtin_amdgcn_global_load_lds((const __attribute__((address_space(1))) void*)g,
                                     (__attribute__((address_space(3))) void*)(lds + base),
                                     16, 0, 0);
  }
}

// Wave-per-row LayerNorm of one 256-col fp32 row -> bf16 LDS tile row r.
__device__ __forceinline__ void ln_row_to_lds(char* dst, const float* __restrict__ src,
                                              const float* __restrict__ g,
                                              const float* __restrict__ bb, int r) {
  const int lane = threadIdx.x & 63;
  const float4 v = *(const float4*)(src + lane * 4);
  float s = v.x + v.y + v.z + v.w;
  #pragma unroll
  for (int o = 32; o; o >>= 1) s += __shfl_xor(s, o);
  const float mu = s * (1.f / 256.f);
  const float d0 = v.x - mu, d1 = v.y - mu, d2 = v.z - mu, d3 = v.w - mu;
  float q = d0 * d0 + d1 * d1 + d2 * d2 + d3 * d3;
  #pragma unroll
  for (int o = 32; o; o >>= 1) q += __shfl_xor(q, o);
  float rs = rsqrtf(q * (1.f / 256.f) + 1e-5f);
  rs = rs * (1.5f - 0.5f * (q * (1.f / 256.f) + 1e-5f) * rs * rs);  // Newton
  const float4 g4 = *(const float4*)(g + lane * 4);
  const float4 b4 = *(const float4*)(bb + lane * 4);
  const int c = lane * 4;
  *(unsigned*)(dst + swz(r, c, 256)) = pk2(d0 * rs * g4.x + b4.x, d1 * rs * g4.y + b4.y);
  *(unsigned*)(dst + swz(r, c + 2, 256)) = pk2(d2 * rs * g4.z + b4.z, d3 * rs * g4.w + b4.w);
}

// ---------------- attention kernel: one block per 8x8 window ----------------
// LDS 147456B: XW[64][256] (LN'd x, later O) | WS 16KB (W-stage, later P0/P1)
//            | QL[64][256] | KL[64][256] | VT[256][64]   (all bf16, swizzled)
__global__ __launch_bounds__(512) void swin_attn(
    const float* __restrict__ x,
    const float* __restrict__ qkv_b, const float* __restrict__ proj_b,
    const float* __restrict__ rpb,
    const float* __restrict__ ln1g, const float* __restrict__ ln1b,
    float* __restrict__ outw)
{
  __shared__ __align__(16) char smem[147456];
  char* XW = smem;
  char* WS = smem + 32768;
  char* QL = smem + 49152;
  char* KL = smem + 81920;
  char* VT = smem + 114688;

  const int t = threadIdx.x;
  const int wv = t >> 6, l = t & 63;
  const int blk = blockIdx.x;
  const int b = blk >> 8, w = blk & 255;
  const int wi = w >> 4, wj = w & 15;

  // Phase 0: gather (roll -4) + LN1 -> XW
  #pragma unroll
  for (int i = 0; i < 8; ++i) {
    const int r = wv * 8 + i;
    const int ui = (wi * 8 + (r >> 3) + 4) & 127;
    const int uj = (wj * 8 + (r & 7) + 4) & 127;
    const long row = ((long)b << 14) + (ui << 7) + uj;
    ln_row_to_lds(XW, x + row * 256, ln1g, ln1b, r);
  }
  __syncthreads();

  const int MB = (wv >> 2) << 4;  // col-tile within a 32-col chunk
  const int NB = (wv & 3) << 4;   // row-tile
  const float SC = 0.17677669529663687f;

  // Phase 1: qkv GEMM in 24 chunks of 32 output cols, K=256
  for (int ch = 0; ch < 24; ++ch) {
    glds_stage<512>(WS, g_wt + ch * 32 * 256, 256, 16384);
    __syncthreads();
    ffrag acc = {0.f, 0.f, 0.f, 0.f};
    #pragma unroll
    for (int ks = 0; ks < 8; ++ks) {
      const bfrag a = ldfrag(WS, MB, ks * 32, 256);
      const bfrag bb = ldfrag(XW, NB, ks * 32, 256);
      acc = MFMA16(a, bb, acc);
    }
    // D: n(row) = lane&15, m(col) = (lane>>4)*4 + reg
    const int r = NB + (l & 15);
    const int cg = ch * 32 + MB + ((l >> 4) << 2);
    const float4 b4 = *(const float4*)(qkv_b + cg);
    float v0 = acc.x + b4.x, v1 = acc.y + b4.y, v2 = acc.z + b4.z, v3 = acc.w + b4.w;
    if (cg < 256) {          // Q (pre-scaled)
      v0 *= SC; v1 *= SC; v2 *= SC; v3 *= SC;
      *(unsigned*)(QL + swz(r, cg, 256)) = pk2(v0, v1);
      *(unsigned*)(QL + swz(r, cg + 2, 256)) = pk2(v2, v3);
    } else if (cg < 512) {   // K
      const int c = cg - 256;
      *(unsigned*)(KL + swz(r, c, 256)) = pk2(v0, v1);
      *(unsigned*)(KL + swz(r, c + 2, 256)) = pk2(v2, v3);
    } else {                 // V, stored transposed [vcol][row]
      const int c = cg - 512;
      *(unsigned short*)(VT + swz(c + 0, r, 64)) = (unsigned short)bf16b(v0);
      *(unsigned short*)(VT + swz(c + 1, r, 64)) = (unsigned short)bf16b(v1);
      *(unsigned short*)(VT + swz(c + 2, r, 64)) = (unsigned short)bf16b(v2);
      *(unsigned short*)(VT + swz(c + 3, r, 64)) = (unsigned short)bf16b(v3);
    }
    __syncthreads();
  }

  // Phase 2: attention, 2 heads in parallel (waves 0-3 / 4-7)
  const int w4 = wv & 3;
  const int half = wv >> 2;
  for (int hp = 0; hp < 4; ++hp) {
    const int h = hp * 2 + half;
    char* PB = WS + half * 8192;   // [64][64] bf16 P-buffer per head
    const int hk = h * 32;

    const bfrag aq = ldfrag(QL, w4 * 16, hk, 256);
    ffrag s[4];
    #pragma unroll
    for (int nt = 0; nt < 4; ++nt) {
      const bfrag bk = ldfrag(KL, nt * 16, hk, 256);
      ffrag z = {0.f, 0.f, 0.f, 0.f};
      s[nt] = MFMA16(aq, bk, z);
    }
    // bias + in-register softmax; row = w4*16+(l>>4)*4+reg, col = nt*16+(l&15)
    const int colb = l & 15;
    const int rbase = w4 * 16 + ((l >> 4) << 2);
    float pr[4][4], mx[4], sm[4];
    #pragma unroll
    for (int reg = 0; reg < 4; ++reg) mx[reg] = -3e38f;
    #pragma unroll
    for (int nt = 0; nt < 4; ++nt) {
      #pragma unroll
      for (int reg = 0; reg < 4; ++reg) {
        const int rr = rbase + reg, cc = nt * 16 + colb;
        const int idx = ((rr >> 3) - (cc >> 3) + 7) * 15 + ((rr & 7) - (cc & 7) + 7);
        pr[nt][reg] = s[nt][reg] + rpb[idx * 8 + h];
        mx[reg] = fmaxf(mx[reg], pr[nt][reg]);
      }
    }
    #pragma unroll
    for (int reg = 0; reg < 4; ++reg) {
      #pragma unroll
      for (int o = 1; o < 16; o <<= 1) mx[reg] = fmaxf(mx[reg], __shfl_xor(mx[reg], o));
      sm[reg] = 0.f;
    }
    #pragma unroll
    for (int nt = 0; nt < 4; ++nt)
      #pragma unroll
      for (int reg = 0; reg < 4; ++reg) {
        pr[nt][reg] = __expf(pr[nt][reg] - mx[reg]);
        sm[reg] += pr[nt][reg];
      }
    #pragma unroll
    for (int reg = 0; reg < 4; ++reg) {
      #pragma unroll
      for (int o = 1; o < 16; o <<= 1) sm[reg] += __shfl_xor(sm[reg], o);
      sm[reg] = 1.f / sm[reg];
    }
    #pragma unroll
    for (int nt = 0; nt < 4; ++nt)
      #pragma unroll
      for (int reg = 0; reg < 4; ++reg)
        *(unsigned short*)(PB + swz(rbase + reg, nt * 16 + colb, 64)) =
            (unsigned short)bf16b(pr[nt][reg] * sm[reg]);
    __syncthreads();

    // PV: A = P [qrow][k=64], B^T = VT [vd][k]; n = vd lane, m = qrow
    ffrag o0 = {0.f, 0.f, 0.f, 0.f}, o1 = {0.f, 0.f, 0.f, 0.f};
    #pragma unroll
    for (int ks = 0; ks < 2; ++ks) {
      const bfrag ap = ldfrag(PB, w4 * 16, ks * 32, 64);
      const bfrag bv0 = ldfrag(VT, hk, ks * 32, 64);
      const bfrag bv1 = ldfrag(VT, hk + 16, ks * 32, 64);
      o0 = MFMA16(ap, bv0, o0);
      o1 = MFMA16(ap, bv1, o1);
    }
    #pragma unroll
    for (int reg = 0; reg < 4; ++reg) {
      *(unsigned short*)(XW + swz(rbase + reg, hk + colb, 256)) = (unsigned short)bf16b(o0[reg]);
      *(unsigned short*)(XW + swz(rbase + reg, hk + 16 + colb, 256)) = (unsigned short)bf16b(o1[reg]);
    }
    __syncthreads();
  }

  // Phase 3: proj in 8 chunks of 32 cols; scatter (roll +4) with proj bias
  for (int ch = 0; ch < 8; ++ch) {
    glds_stage<512>(WS, g_wt + 196608 + ch * 32 * 256, 256, 16384);
    __syncthreads();
    ffrag acc = {0.f, 0.f, 0.f, 0.f};
    #pragma unroll
    for (int ks = 0; ks < 8; ++ks) {
      const bfrag a = ldfrag(WS, MB, ks * 32, 256);
      const bfrag bo = ldfrag(XW, NB, ks * 32, 256);
      acc = MFMA16(a, bo, acc);
    }
    const int r = NB + (l & 15);
    const int c0 = ch * 32 + MB + ((l >> 4) << 2);
    const float4 pb4 = *(const float4*)(proj_b + c0);
    const int ui = (wi * 8 + (r >> 3) + 4) & 127;
    const int uj = (wj * 8 + (r & 7) + 4) & 127;
    const long row = ((long)b << 14) + (ui << 7) + uj;
    float4 o4;
    o4.x = acc.x + pb4.x; o4.y = acc.y + pb4.y;
    o4.z = acc.z + pb4.z; o4.w = acc.w + pb4.w;
    *(float4*)(outw + row * 256 + c0) = o4;
    __syncthreads();
  }
}

// ---------------- MLP kernel: one block per 64 rows, 2 blocks/CU ----------------
// LDS 73728B: H2[64][256] 32KB | WS 32KB (w1 [64][256] / w2 [256][64]) | HD[64][64] 8KB
__global__ __launch_bounds__(512, 4) void swin_mlp(
    const float* __restrict__ x, const float* __restrict__ outw,
    const float* __restrict__ ln2g, const float* __restrict__ ln2b,
    const float* __restrict__ b1, const float* __restrict__ b2,
    float* __restrict__ y)
{
  __shared__ __align__(16) char smem[73728];
  char* H2 = smem;
  char* WS = smem + 32768;
  char* HD = smem + 65536;
  const int t = threadIdx.x, wv = t >> 6, l = t & 63;
  const long base = (long)blockIdx.x << 6;

  #pragma unroll
  for (int i = 0; i < 8; ++i) {
    const int r = wv * 8 + i;
    ln_row_to_lds(H2, outw + (base + r) * 256, ln2g, ln2b, r);
  }
  __syncthreads();

  const int mq = wv >> 1;            // GEMM1 col-tile (0..3)
  const int nq = (wv & 1) << 1;      // GEMM1 row-tile pair base (0 or 2)

  ffrag acc2[2][4];
  {
    ffrag z = {0.f, 0.f, 0.f, 0.f};
    #pragma unroll
    for (int mt = 0; mt < 2; ++mt)
      #pragma unroll
      for (int nt = 0; nt < 4; ++nt) acc2[mt][nt] = z;
  }

  for (int ch = 0; ch < 16; ++ch) {
    // stage w1 chunk [64 outcols][256 k]
    glds_stage<512>(WS, g_wt + 262144 + ch * 64 * 256, 256, 32768);
    __syncthreads();
    ffrag a1[2];
    {
      ffrag z = {0.f, 0.f, 0.f, 0.f};
      a1[0] = z; a1[1] = z;
    }
    #pragma unroll
    for (int ks = 0; ks < 8; ++ks) {
      const bfrag a = ldfrag(WS, mq * 16, ks * 32, 256);
      const bfrag bb0 = ldfrag(H2, nq * 16, ks * 32, 256);
      const bfrag bb1 = ldfrag(H2, (nq + 1) * 16, ks * 32, 256);
      a1[0] = MFMA16(a, bb0, a1[0]);
      a1[1] = MFMA16(a, bb1, a1[1]);
    }
    __syncthreads();   // WS(w1) reads done

    // bias + exact GELU -> HD; then stage w2 chunk [256 outcols][64 k]
    const int c0 = mq * 16 + ((l >> 4) << 2);
    const float4 b14 = *(const float4*)(b1 + ch * 64 + c0);
    #pragma unroll
    for (int nt = 0; nt < 2; ++nt) {
      const int rr = (nq + nt) * 16 + (l & 15);
      const float u0 = a1[nt][0] + b14.x, u1 = a1[nt][1] + b14.y;
      const float u2 = a1[nt][2] + b14.z, u3 = a1[nt][3] + b14.w;
      const float g0 = 0.5f * u0 * (1.f + erff(u0 * 0.70710678118654752f));
      const float g1 = 0.5f * u1 * (1.f + erff(u1 * 0.70710678118654752f));
      const float g2 = 0.5f * u2 * (1.f + erff(u2 * 0.70710678118654752f));
      const float g3 = 0.5f * u3 * (1.f + erff(u3 * 0.70710678118654752f));
      *(unsigned*)(HD + swz(rr, c0, 64)) = pk2(g0, g1);
      *(unsigned*)(HD + swz(rr, c0 + 2, 64)) = pk2(g2, g3);
    }
    glds_stage<128>(WS, g_wt + 524288 + ch * 64, 1024, 32768);
    __syncthreads();

    // GEMM2: wave handles outcols wv*32..+31 (m-tiles 2wv, 2wv+1), all 4 n-tiles
    #pragma unroll
    for (int ks = 0; ks < 2; ++ks) {
      const bfrag am0 = ldfrag(WS, (wv * 2) * 16, ks * 32, 64);
      const bfrag am1 = ldfrag(WS, (wv * 2 + 1) * 16, ks * 32, 64);
      #pragma unroll
      for (int nt = 0; nt < 4; ++nt) {
        const bfrag bb = ldfrag(HD, nt * 16, ks * 32, 64);
        acc2[0][nt] = MFMA16(am0, bb, acc2[0][nt]);
        acc2[1][nt] = MFMA16(am1, bb, acc2[1][nt]);
      }
    }
    __syncthreads();   // WS(w2)/HD reads done before next chunk
  }

  // epilogue: y = x + outw + mlp
  #pragma unroll
  for (int mt = 0; mt < 2; ++mt) {
    const int c0 = (wv * 2 + mt) * 16 + ((l >> 4) << 2);
    const float4 b24 = *(const float4*)(b2 + c0);
    #pragma unroll
    for (int nt = 0; nt < 4; ++nt) {
      const long row = base + nt * 16 + (l & 15);
      const float4 xv = *(const float4*)(x + row * 256 + c0);
      const float4 ov = *(const float4*)(outw + row * 256 + c0);
      float4 res;
      res.x = xv.x + ov.x + acc2[mt][nt][0] + b24.x;
      res.y = xv.y + ov.y + acc2[mt][nt][1] + b24.y;
      res.z = xv.z + ov.z + acc2[mt][nt][2] + b24.z;
      res.w = xv.w + ov.w + acc2[mt][nt][3] + b24.w;
      *(float4*)(y + row * 256 + c0) = res;
    }
  }
}

extern "C" void kernel_launch(void* const* d_in, const int* in_sizes, int n_in,
                              void* d_out, int out_size, void* d_ws, size_t ws_size,
                              hipStream_t stream) {
  (void)in_sizes; (void)n_in; (void)out_size; (void)ws_size;
  const float* x      = (const float*)d_in[0];
  const float* qkv_w  = (const float*)d_in[1];
  const float* qkv_b  = (const float*)d_in[2];
  const float* proj_w = (const float*)d_in[3];
  const float* proj_b = (const float*)d_in[4];
  const float* rpb    = (const float*)d_in[5];
  const float* ln1g   = (const float*)d_in[6];
  const float* ln1b   = (const float*)d_in[7];
  const float* ln2g   = (const float*)d_in[8];
  const float* ln2b   = (const float*)d_in[9];
  const float* b1     = (const float*)d_in[11];
  const float* w2     = (const float*)d_in[12];
  const float* b2     = (const float*)d_in[13];
  const float* w1     = (const float*)d_in[10];
  float* y    = (float*)d_out;
  float* outw = (float*)d_ws;  // attention-branch output, (B*L, 256) fp32

  hipLaunchKernelGGL(conv_w, dim3(1536), dim3(256), 0, stream, qkv_w, proj_w, w1, w2);
  hipLaunchKernelGGL(swin_attn, dim3(4096), dim3(512), 0, stream,
                     x, qkv_b, proj_b, rpb, ln1g, ln1b, outw);
  hipLaunchKernelGGL(swin_mlp, dim3(4096), dim3(512), 0, stream,
                     x, outw, ln2g, ln2b, b1, b2, y);
}

// Round 7
// 1301.429 us; speedup vs baseline: 69.7109x; 1.0956x over previous
//
#include <hip/hip_runtime.h>
#include <math.h>

typedef short bfrag __attribute__((ext_vector_type(8)));   // 8 bf16 (4 VGPR)
typedef float ffrag __attribute__((ext_vector_type(4)));   // 4 f32 accum

#define MFMA16(a, b, c) __builtin_amdgcn_mfma_f32_16x16x32_bf16((a), (b), (c), 0, 0, 0)

// Pre-transposed bf16 weights ([outcol][k] row-major), built once by conv_w.
// qkv @0 (768x256), proj @196608 (256x256), w1 @262144 (1024x256), w2 @524288 (256x1024)
__device__ __align__(16) unsigned short g_wt[786432];

__device__ __forceinline__ unsigned bf16b(float f) {   // fp32 -> bf16 bits, RNE
  unsigned u = __float_as_uint(f);
  return (u + 0x7FFFu + ((u >> 16) & 1u)) >> 16;
}
__device__ __forceinline__ unsigned pk2(float lo, float hi) {
  return bf16b(lo) | (bf16b(hi) << 16);
}
__device__ __forceinline__ float bf2f(unsigned u) {
  return __uint_as_float(u << 16);
}

__global__ void conv_w(const float* __restrict__ qkv_w, const float* __restrict__ proj_w,
                       const float* __restrict__ w1, const float* __restrict__ w2) {
  const int idx = blockIdx.x * 256 + threadIdx.x;   // 393216 (c,k2) pairs
  const float* src; int c, k2, C, K, ofs;
  if (idx < 98304)       { src = qkv_w;  C = 768;  K = 256;  c = idx % 768;  k2 = idx / 768;  ofs = 0; }
  else if (idx < 131072) { int i = idx - 98304;  src = proj_w; C = 256;  K = 256;  c = i % 256;  k2 = i / 256;  ofs = 196608; }
  else if (idx < 262144) { int i = idx - 131072; src = w1;     C = 1024; K = 256;  c = i % 1024; k2 = i / 1024; ofs = 262144; }
  else                   { int i = idx - 262144; src = w2;     C = 256;  K = 1024; c = i % 256;  k2 = i / 256;  ofs = 524288; }
  const float lo = src[(2 * k2) * C + c];
  const float hi = src[(2 * k2 + 1) * C + c];
  *(unsigned*)&g_wt[ofs + c * K + 2 * k2] = pk2(lo, hi);
}

// Byte offset into [*][C] bf16 LDS tile, XOR-swizzled per 16B slot.
__device__ __forceinline__ int swz(int row, int col, int C) {
  return row * (C * 2) + ((((col >> 3) ^ (row & 7)) << 4) + ((col & 7) << 1));
}
__device__ __forceinline__ bfrag ldfrag(const char* lds, int outer, int k0, int C) {
  const int l = threadIdx.x & 63;
  return *(const bfrag*)(lds + swz(outer + (l & 15), k0 + ((l >> 4) << 3), C));
}

// Stage a [128][256] bf16 tile (64KB) from a k-major global matrix into swizzled
// LDS: linear LDS dest + inverse-swizzled per-lane global source (rule #21).
__device__ __forceinline__ void stage_tile(char* lds, const unsigned short* __restrict__ src,
                                           long rowBase, int strideShorts, int kOfs) {
  const int wv = threadIdx.x >> 6, l = threadIdx.x & 63;
  #pragma unroll
  for (int p = 0; p < 8; ++p) {
    const int base = wv * 1024 + p * 8192;
    const int off = base + l * 16;
    const int row = off >> 9;
    const int ss = ((off & 511) >> 4) ^ (row & 7);
    const unsigned short* g = src + (rowBase + row) * (long)strideShorts + kOfs + ss * 8;
    __builtin_amdgcn_global_load_lds((const __attribute__((address_space(1))) void*)g,
                                     (__attribute__((address_space(3))) void*)(lds + base),
                                     16, 0, 0);
  }
}

// Generic weight-tile stage (DSTROWB = LDS row bytes). src already chunk-offset.
template <int DSTROWB>
__device__ __forceinline__ void glds_stage(char* lds, const unsigned short* src,
                                           int srcRowShorts, int bytes) {
  const int wv = threadIdx.x >> 6, l = threadIdx.x & 63;
  for (int base = wv * 1024; base < bytes; base += 8192) {
    const int off = base + l * 16;
    const int row = off / DSTROWB;
    const int slot = (off % DSTROWB) >> 4;
    const int ss = slot ^ (row & 7);
    const unsigned short* g = src + row * srcRowShorts + ss * 8;
    __builtin_amdgcn_global_load_lds((const __attribute__((address_space(1))) void*)g,
                                     (__attribute__((address_space(3))) void*)(lds + base),
                                     16, 0, 0);
  }
}

// 128x128 tile core: A-frag from BW (weights, m=outcol), B-frag from AX (rows).
__device__ __forceinline__ void mm_core(const char* AX, const char* BW, ffrag acc[2][4]) {
  const int wv = threadIdx.x >> 6;
  const int rh = wv >> 2, cq = wv & 3;
  #pragma unroll
  for (int ks = 0; ks < 8; ++ks) {
    const bfrag aw0 = ldfrag(BW, cq * 32, ks * 32, 256);
    const bfrag aw1 = ldfrag(BW, cq * 32 + 16, ks * 32, 256);
    #pragma unroll
    for (int nt = 0; nt < 4; ++nt) {
      const bfrag xb = ldfrag(AX, rh * 64 + nt * 16, ks * 32, 256);
      acc[0][nt] = MFMA16(aw0, xb, acc[0][nt]);
      acc[1][nt] = MFMA16(aw1, xb, acc[1][nt]);
    }
  }
}

// Wave-per-row LayerNorm: 4 elems/lane in, two packed bf16 words out.
__device__ __forceinline__ void ln_pack(float d0, float d1, float d2, float d3,
                                        const float* g, const float* bb, int lane,
                                        unsigned& o0, unsigned& o1) {
  float s = d0 + d1 + d2 + d3;
  #pragma unroll
  for (int o = 32; o; o >>= 1) s += __shfl_xor(s, o);
  const float mu = s * (1.f / 256.f);
  d0 -= mu; d1 -= mu; d2 -= mu; d3 -= mu;
  float q = d0 * d0 + d1 * d1 + d2 * d2 + d3 * d3;
  #pragma unroll
  for (int o = 32; o; o >>= 1) q += __shfl_xor(q, o);
  const float vv = q * (1.f / 256.f) + 1e-5f;
  float rs = rsqrtf(vv);
  rs = rs * (1.5f - 0.5f * vv * rs * rs);
  const float4 g4 = *(const float4*)(g + lane * 4);
  const float4 b4 = *(const float4*)(bb + lane * 4);
  o0 = pk2(d0 * rs * g4.x + b4.x, d1 * rs * g4.y + b4.y);
  o1 = pk2(d2 * rs * g4.z + b4.z, d3 * rs * g4.w + b4.w);
}

// LN1 for one batch-group: 8192 blocks x 8 rows. Reads x at rowOfs+, writes XB local.
__global__ __launch_bounds__(512) void ln1_k(const float* __restrict__ x,
    const float* __restrict__ g, const float* __restrict__ bb,
    unsigned short* __restrict__ XB, long rowOfs) {
  const int wv = threadIdx.x >> 6, l = threadIdx.x & 63;
  const long lrow = (long)blockIdx.x * 8 + wv;
  const float4 v = *(const float4*)(x + (rowOfs + lrow) * 256 + l * 4);
  unsigned o0, o1;
  ln_pack(v.x, v.y, v.z, v.w, g, bb, l, o0, o1);
  unsigned short* dp = XB + lrow * 256 + l * 4;
  *(unsigned*)dp = o0; *(unsigned*)(dp + 2) = o1;
}

// qkv GEMM for one group: grid (512, 6), M=65536 local rows, N=768, K=256.
__global__ __launch_bounds__(512) void gemm_qkv(const unsigned short* __restrict__ XB,
    const float* __restrict__ qkv_b, unsigned short* __restrict__ QKV) {
  __shared__ __align__(16) char smem[131072];
  char* AX = smem; char* BW = smem + 65536;
  const int mb = blockIdx.x, nb = blockIdx.y;
  stage_tile(AX, XB, (long)mb * 128, 256, 0);
  stage_tile(BW, g_wt, nb * 128, 256, 0);
  __syncthreads();
  ffrag acc[2][4];
  #pragma unroll
  for (int a = 0; a < 2; ++a)
    #pragma unroll
    for (int n = 0; n < 4; ++n) { ffrag z = {0.f, 0.f, 0.f, 0.f}; acc[a][n] = z; }
  mm_core(AX, BW, acc);
  const int l = threadIdx.x & 63, wv = threadIdx.x >> 6;
  const int rh = wv >> 2, cq = wv & 3;
  const float sc = (nb < 2) ? 0.17677669529663687f : 1.f;   // Q pre-scale
  #pragma unroll
  for (int mt = 0; mt < 2; ++mt) {
    const int cg = nb * 128 + cq * 32 + mt * 16 + ((l >> 4) << 2);
    const float4 bq = *(const float4*)(qkv_b + cg);
    #pragma unroll
    for (int nt = 0; nt < 4; ++nt) {
      const long row = (long)mb * 128 + rh * 64 + nt * 16 + (l & 15);
      unsigned short* dp = QKV + row * 768 + cg;
      *(unsigned*)dp       = pk2((acc[mt][nt][0] + bq.x) * sc, (acc[mt][nt][1] + bq.y) * sc);
      *(unsigned*)(dp + 2) = pk2((acc[mt][nt][2] + bq.z) * sc, (acc[mt][nt][3] + bq.w) * sc);
    }
  }
}

// proj GEMM: full M=262144, grid (2048, 2). Obuf -> outw (bf16).
__global__ __launch_bounds__(512) void gemm_proj(const unsigned short* __restrict__ O,
    const float* __restrict__ proj_b, unsigned short* __restrict__ outw) {
  __shared__ __align__(16) char smem[131072];
  char* AX = smem; char* BW = smem + 65536;
  const int mb = blockIdx.x, nb = blockIdx.y;
  stage_tile(AX, O, (long)mb * 128, 256, 0);
  stage_tile(BW, g_wt + 196608, nb * 128, 256, 0);
  __syncthreads();
  ffrag acc[2][4];
  #pragma unroll
  for (int a = 0; a < 2; ++a)
    #pragma unroll
    for (int n = 0; n < 4; ++n) { ffrag z = {0.f, 0.f, 0.f, 0.f}; acc[a][n] = z; }
  mm_core(AX, BW, acc);
  const int l = threadIdx.x & 63, wv = threadIdx.x >> 6;
  const int rh = wv >> 2, cq = wv & 3;
  #pragma unroll
  for (int mt = 0; mt < 2; ++mt) {
    const int cg = nb * 128 + cq * 32 + mt * 16 + ((l >> 4) << 2);
    const float4 pb = *(const float4*)(proj_b + cg);
    #pragma unroll
    for (int nt = 0; nt < 4; ++nt) {
      const long row = (long)mb * 128 + rh * 64 + nt * 16 + (l & 15);
      unsigned short* dp = outw + row * 256 + cg;
      *(unsigned*)dp       = pk2(acc[mt][nt][0] + pb.x, acc[mt][nt][1] + pb.y);
      *(unsigned*)(dp + 2) = pk2(acc[mt][nt][2] + pb.z, acc[mt][nt][3] + pb.w);
    }
  }
}

// ---- attention core: one block per 8x8 window (1024 blocks/group) ----
// LDS 80KB: KL[64][256] 32K | VT[256][64] 32K | PB 8 x [16][64] 16K  -> 2 blocks/CU
__global__ __launch_bounds__(512, 4) void attn_core(const unsigned short* __restrict__ QKV,
    const float* __restrict__ rpb, unsigned short* __restrict__ O, int bofs) {
  __shared__ __align__(16) char smem[81920];
  char* KL = smem;
  char* VT = smem + 32768;
  char* PB = smem + 65536;
  const int t = threadIdx.x, wv = t >> 6, l = t & 63;
  const int blk = blockIdx.x;
  const int b = blk >> 8, w = blk & 255;   // b = local batch 0..3
  const int wi = w >> 4, wj = w & 15;
  const int bi0 = wi * 8 + 4, bj0 = wj * 8 + 4;
  const ffrag ZERO4 = {0.f, 0.f, 0.f, 0.f};

  #define SROW(r) (((long)b << 14) + (((bi0 + ((r) >> 3)) & 127) << 7) + ((bj0 + ((r) & 7)) & 127))
  #define GROW(r) (((long)(bofs + b) << 14) + (((bi0 + ((r) >> 3)) & 127) << 7) + ((bj0 + ((r) & 7)) & 127))

  // stage K rows -> KL (swizzled via pre-swizzled source)
  #pragma unroll
  for (int p = 0; p < 4; ++p) {
    const int base = wv * 1024 + p * 8192;
    const int off = base + l * 16;
    const int kv = off >> 9;
    const int ss = ((off & 511) >> 4) ^ (kv & 7);
    const unsigned short* g = QKV + SROW(kv) * 768 + 256 + ss * 8;
    __builtin_amdgcn_global_load_lds((const __attribute__((address_space(1))) void*)g,
                                     (__attribute__((address_space(3))) void*)(KL + base),
                                     16, 0, 0);
  }

  // stage V -> VT transposed (packed b32 writes)
  {
    const int rp = t & 31, dh = t >> 5;              // row-pair, d-hextet
    const unsigned short* v0p = QKV + SROW(2 * rp) * 768 + 512 + dh * 16;
    const unsigned short* v1p = QKV + SROW(2 * rp + 1) * 768 + 512 + dh * 16;
    const bfrag a0 = *(const bfrag*)v0p, a1 = *(const bfrag*)(v0p + 8);
    const bfrag c0 = *(const bfrag*)v1p, c1 = *(const bfrag*)(v1p + 8);
    #pragma unroll
    for (int j = 0; j < 8; ++j) {
      const unsigned w0 = ((unsigned)(unsigned short)a0[j]) | (((unsigned)(unsigned short)c0[j]) << 16);
      const unsigned w1 = ((unsigned)(unsigned short)a1[j]) | (((unsigned)(unsigned short)c1[j]) << 16);
      *(unsigned*)(VT + swz(dh * 16 + j, 2 * rp, 64)) = w0;
      *(unsigned*)(VT + swz(dh * 16 + 8 + j, 2 * rp, 64)) = w1;
    }
  }
  __syncthreads();

  const int qt = wv & 3, hh = wv >> 2;
  char* myPB = PB + wv * 2048;
  const int colb = l & 15;
  const int rbase = qt * 16 + ((l >> 4) << 2);

  for (int i = 0; i < 4; ++i) {
    const int h = 2 * i + hh;
    const int hk = h * 32;
    const int qr = qt * 16 + (l & 15);
    const bfrag aq = *(const bfrag*)(QKV + SROW(qr) * 768 + hk + ((l >> 4) << 3));
    ffrag s[4];
    #pragma unroll
    for (int nt = 0; nt < 4; ++nt) {
      const bfrag bk = ldfrag(KL, nt * 16, hk, 256);
      s[nt] = MFMA16(aq, bk, ZERO4);
    }
    float pr[4][4], mx[4], sm[4];
    #pragma unroll
    for (int reg = 0; reg < 4; ++reg) mx[reg] = -3e38f;
    #pragma unroll
    for (int nt = 0; nt < 4; ++nt)
      #pragma unroll
      for (int reg = 0; reg < 4; ++reg) {
        const int rr = rbase + reg, cc = nt * 16 + colb;
        const int idx = ((rr >> 3) - (cc >> 3) + 7) * 15 + ((rr & 7) - (cc & 7) + 7);
        pr[nt][reg] = s[nt][reg] + rpb[idx * 8 + h];
        mx[reg] = fmaxf(mx[reg], pr[nt][reg]);
      }
    #pragma unroll
    for (int reg = 0; reg < 4; ++reg) {
      #pragma unroll
      for (int o = 1; o < 16; o <<= 1) mx[reg] = fmaxf(mx[reg], __shfl_xor(mx[reg], o));
      sm[reg] = 0.f;
    }
    #pragma unroll
    for (int nt = 0; nt < 4; ++nt)
      #pragma unroll
      for (int reg = 0; reg < 4; ++reg) {
        pr[nt][reg] = __expf(pr[nt][reg] - mx[reg]);
        sm[reg] += pr[nt][reg];
      }
    #pragma unroll
    for (int reg = 0; reg < 4; ++reg) {
      #pragma unroll
      for (int o = 1; o < 16; o <<= 1) sm[reg] += __shfl_xor(sm[reg], o);
      sm[reg] = 1.f / sm[reg];
    }
    #pragma unroll
    for (int nt = 0; nt < 4; ++nt)
      #pragma unroll
      for (int reg = 0; reg < 4; ++reg)
        *(unsigned short*)(myPB + swz(((l >> 4) << 2) + reg, nt * 16 + colb, 64)) =
            (unsigned short)bf16b(pr[nt][reg] * sm[reg]);

    ffrag o0 = ZERO4, o1 = ZERO4;
    #pragma unroll
    for (int ks = 0; ks < 2; ++ks) {
      const bfrag ap = ldfrag(myPB, 0, ks * 32, 64);
      const bfrag bv0 = ldfrag(VT, hk, ks * 32, 64);
      const bfrag bv1 = ldfrag(VT, hk + 16, ks * 32, 64);
      o0 = MFMA16(ap, bv0, o0);
      o1 = MFMA16(ap, bv1, o1);
    }
    #pragma unroll
    for (int reg = 0; reg < 4; ++reg) {
      const long orow = GROW(rbase + reg);
      O[orow * 256 + hk + colb] = (unsigned short)bf16b(o0[reg]);
      O[orow * 256 + hk + 16 + colb] = (unsigned short)bf16b(o1[reg]);
    }
  }
  #undef SROW
  #undef GROW
}

// ---- fused MLP (validated in round 4), outw now bf16. 4096 blocks x 64 rows ----
// LDS 73728B: H2[64][256] 32K | WS 32K | HD[64][64] 8K  -> 2 blocks/CU
__global__ __launch_bounds__(512, 4) void swin_mlp(
    const float* __restrict__ x, const unsigned short* __restrict__ outw,
    const float* __restrict__ ln2g, const float* __restrict__ ln2b,
    const float* __restrict__ b1, const float* __restrict__ b2,
    float* __restrict__ y)
{
  __shared__ __align__(16) char smem[73728];
  char* H2 = smem;
  char* WS = smem + 32768;
  char* HD = smem + 65536;
  const int t = threadIdx.x, wv = t >> 6, l = t & 63;
  const long base = (long)blockIdx.x << 6;

  #pragma unroll
  for (int i = 0; i < 8; ++i) {
    const int r = wv * 8 + i;
    const uint2 raw = *(const uint2*)(outw + (base + r) * 256 + l * 4);
    unsigned o0, o1;
    ln_pack(bf2f(raw.x & 0xFFFFu), bf2f(raw.x >> 16), bf2f(raw.y & 0xFFFFu), bf2f(raw.y >> 16),
            ln2g, ln2b, l, o0, o1);
    *(unsigned*)(H2 + swz(r, l * 4, 256)) = o0;
    *(unsigned*)(H2 + swz(r, l * 4 + 2, 256)) = o1;
  }
  __syncthreads();

  const int mq = wv >> 1, nq = (wv & 1) << 1;

  ffrag acc2[2][4];
  #pragma unroll
  for (int mt = 0; mt < 2; ++mt)
    #pragma unroll
    for (int nt = 0; nt < 4; ++nt) { ffrag z = {0.f, 0.f, 0.f, 0.f}; acc2[mt][nt] = z; }

  for (int ch = 0; ch < 16; ++ch) {
    glds_stage<512>(WS, g_wt + 262144 + ch * 64 * 256, 256, 32768);
    __syncthreads();
    ffrag a1[2];
    { ffrag z = {0.f, 0.f, 0.f, 0.f}; a1[0] = z; a1[1] = z; }
    #pragma unroll
    for (int ks = 0; ks < 8; ++ks) {
      const bfrag a = ldfrag(WS, mq * 16, ks * 32, 256);
      const bfrag bb0 = ldfrag(H2, nq * 16, ks * 32, 256);
      const bfrag bb1 = ldfrag(H2, (nq + 1) * 16, ks * 32, 256);
      a1[0] = MFMA16(a, bb0, a1[0]);
      a1[1] = MFMA16(a, bb1, a1[1]);
    }
    __syncthreads();   // WS(w1) reads done

    const int c0 = mq * 16 + ((l >> 4) << 2);
    const float4 b14 = *(const float4*)(b1 + ch * 64 + c0);
    #pragma unroll
    for (int nt = 0; nt < 2; ++nt) {
      const int rr = (nq + nt) * 16 + (l & 15);
      const float u0 = a1[nt][0] + b14.x, u1 = a1[nt][1] + b14.y;
      const float u2 = a1[nt][2] + b14.z, u3 = a1[nt][3] + b14.w;
      const float g0 = 0.5f * u0 * (1.f + erff(u0 * 0.70710678118654752f));
      const float g1 = 0.5f * u1 * (1.f + erff(u1 * 0.70710678118654752f));
      const float g2 = 0.5f * u2 * (1.f + erff(u2 * 0.70710678118654752f));
      const float g3 = 0.5f * u3 * (1.f + erff(u3 * 0.70710678118654752f));
      *(unsigned*)(HD + swz(rr, c0, 64)) = pk2(g0, g1);
      *(unsigned*)(HD + swz(rr, c0 + 2, 64)) = pk2(g2, g3);
    }
    glds_stage<128>(WS, g_wt + 524288 + ch * 64, 1024, 32768);
    __syncthreads();

    #pragma unroll
    for (int ks = 0; ks < 2; ++ks) {
      const bfrag am0 = ldfrag(WS, (wv * 2) * 16, ks * 32, 64);
      const bfrag am1 = ldfrag(WS, (wv * 2 + 1) * 16, ks * 32, 64);
      #pragma unroll
      for (int nt = 0; nt < 4; ++nt) {
        const bfrag bb = ldfrag(HD, nt * 16, ks * 32, 64);
        acc2[0][nt] = MFMA16(am0, bb, acc2[0][nt]);
        acc2[1][nt] = MFMA16(am1, bb, acc2[1][nt]);
      }
    }
    __syncthreads();   // WS/HD reads done before next chunk
  }

  #pragma unroll
  for (int mt = 0; mt < 2; ++mt) {
    const int c0 = (wv * 2 + mt) * 16 + ((l >> 4) << 2);
    const float4 b24 = *(const float4*)(b2 + c0);
    #pragma unroll
    for (int nt = 0; nt < 4; ++nt) {
      const long row = base + nt * 16 + (l & 15);
      const float4 xv = *(const float4*)(x + row * 256 + c0);
      const uint2 ov = *(const uint2*)(outw + row * 256 + c0);
      float4 res;
      res.x = acc2[mt][nt][0] + b24.x + xv.x + bf2f(ov.x & 0xFFFFu);
      res.y = acc2[mt][nt][1] + b24.y + xv.y + bf2f(ov.x >> 16);
      res.z = acc2[mt][nt][2] + b24.z + xv.z + bf2f(ov.y & 0xFFFFu);
      res.w = acc2[mt][nt][3] + b24.w + xv.w + bf2f(ov.y >> 16);
      *(float4*)(y + row * 256 + c0) = res;
    }
  }
}

extern "C" void kernel_launch(void* const* d_in, const int* in_sizes, int n_in,
                              void* d_out, int out_size, void* d_ws, size_t ws_size,
                              hipStream_t stream) {
  (void)in_sizes; (void)n_in; (void)out_size; (void)ws_size;
  const float* x      = (const float*)d_in[0];
  const float* qkv_w  = (const float*)d_in[1];
  const float* qkv_b  = (const float*)d_in[2];
  const float* proj_w = (const float*)d_in[3];
  const float* proj_b = (const float*)d_in[4];
  const float* rpb    = (const float*)d_in[5];
  const float* ln1g   = (const float*)d_in[6];
  const float* ln1b   = (const float*)d_in[7];
  const float* ln2g   = (const float*)d_in[8];
  const float* ln2b   = (const float*)d_in[9];
  const float* w1     = (const float*)d_in[10];
  const float* b1     = (const float*)d_in[11];
  const float* w2     = (const float*)d_in[12];
  const float* b2     = (const float*)d_in[13];
  float* y = (float*)d_out;
  char* ws = (char*)d_ws;

  // Workspace (peak exactly 268,435,456 B = round-2-proven budget):
  //   phase A (per 4-batch group): XB [0,32M) | QKV [32M,128M) | Obuf [128M,256M)
  //   phase B: outw bf16 [0,128M) over dead XB/QKV; Obuf consumed by proj.
  unsigned short* XB   = (unsigned short*)(ws);
  unsigned short* QKV  = (unsigned short*)(ws + 33554432);
  unsigned short* Obuf = (unsigned short*)(ws + 134217728);
  unsigned short* outw = (unsigned short*)(ws);

  hipLaunchKernelGGL(conv_w, dim3(1536), dim3(256), 0, stream, qkv_w, proj_w, w1, w2);
  for (int g = 0; g < 4; ++g) {
    hipLaunchKernelGGL(ln1_k, dim3(8192), dim3(512), 0, stream,
                       x, ln1g, ln1b, XB, (long)g * 65536);
    hipLaunchKernelGGL(gemm_qkv, dim3(512, 6), dim3(512), 0, stream, XB, qkv_b, QKV);
    hipLaunchKernelGGL(attn_core, dim3(1024), dim3(512), 0, stream, QKV, rpb, Obuf, g * 4);
  }
  hipLaunchKernelGGL(gemm_proj, dim3(2048, 2), dim3(512), 0, stream, Obuf, proj_b, outw);
  hipLaunchKernelGGL(swin_mlp, dim3(4096), dim3(512), 0, stream,
                     x, outw, ln2g, ln2b, b1, b2, y);
}

// Round 8
// 1238.454 us; speedup vs baseline: 73.2557x; 1.0508x over previous
//
#include <hip/hip_runtime.h>
#include <math.h>

typedef short bfrag __attribute__((ext_vector_type(8)));   // 8 bf16 (4 VGPR)
typedef float ffrag __attribute__((ext_vector_type(4)));   // 4 f32 accum

#define MFMA16(a, b, c) __builtin_amdgcn_mfma_f32_16x16x32_bf16((a), (b), (c), 0, 0, 0)

// Pre-transposed bf16 weights ([outcol][k] row-major), built once by conv_w.
// qkv @0 (768x256), proj @196608 (256x256), w1 @262144 (1024x256), w2 @524288 (256x1024)
__device__ __align__(16) unsigned short g_wt[786432];

__device__ __forceinline__ unsigned bf16b(float f) {   // fp32 -> bf16 bits, RNE
  unsigned u = __float_as_uint(f);
  return (u + 0x7FFFu + ((u >> 16) & 1u)) >> 16;
}
__device__ __forceinline__ unsigned pk2(float lo, float hi) {
  return bf16b(lo) | (bf16b(hi) << 16);
}
__device__ __forceinline__ float bf2f(unsigned u) {
  return __uint_as_float(u << 16);
}
// tanh-form GELU: u * sigmoid(1.59577(u + 0.044715 u^3)). ~10 VALU vs erff ~30.
__device__ __forceinline__ float gelu_t(float u) {
  const float z = 1.5957691216057308f * (u + 0.044715f * u * u * u);
  return u / (1.f + __expf(-z));
}

__global__ void conv_w(const float* __restrict__ qkv_w, const float* __restrict__ proj_w,
                       const float* __restrict__ w1, const float* __restrict__ w2) {
  const int idx = blockIdx.x * 256 + threadIdx.x;   // 393216 (c,k2) pairs
  const float* src; int c, k2, C, K, ofs;
  if (idx < 98304)       { src = qkv_w;  C = 768;  K = 256;  c = idx % 768;  k2 = idx / 768;  ofs = 0; }
  else if (idx < 131072) { int i = idx - 98304;  src = proj_w; C = 256;  K = 256;  c = i % 256;  k2 = i / 256;  ofs = 196608; }
  else if (idx < 262144) { int i = idx - 131072; src = w1;     C = 1024; K = 256;  c = i % 1024; k2 = i / 1024; ofs = 262144; }
  else                   { int i = idx - 262144; src = w2;     C = 256;  K = 1024; c = i % 256;  k2 = i / 256;  ofs = 524288; }
  const float lo = src[(2 * k2) * C + c];
  const float hi = src[(2 * k2 + 1) * C + c];
  *(unsigned*)&g_wt[ofs + c * K + 2 * k2] = pk2(lo, hi);
}

// Byte offset into [*][C] bf16 LDS tile, XOR-swizzled per 16B slot.
__device__ __forceinline__ int swz(int row, int col, int C) {
  return row * (C * 2) + ((((col >> 3) ^ (row & 7)) << 4) + ((col & 7) << 1));
}
__device__ __forceinline__ bfrag ldfrag(const char* lds, int outer, int k0, int C) {
  const int l = threadIdx.x & 63;
  return *(const bfrag*)(lds + swz(outer + (l & 15), k0 + ((l >> 4) << 3), C));
}

// Stage a [128][128] bf16 tile (32KB): linear LDS dest + inverse-swizzled source.
__device__ __forceinline__ void stage128(char* lds, const unsigned short* __restrict__ src,
                                         long rowBase, int strideShorts, int kOfs) {
  const int wv = threadIdx.x >> 6, l = threadIdx.x & 63;
  #pragma unroll
  for (int p = 0; p < 4; ++p) {
    const int base = wv * 1024 + p * 8192;
    const int off = base + l * 16;
    const int row = off >> 8;
    const int ss = ((off & 255) >> 4) ^ (row & 7);
    const unsigned short* g = src + (rowBase + row) * (long)strideShorts + kOfs + ss * 8;
    __builtin_amdgcn_global_load_lds((const __attribute__((address_space(1))) void*)g,
                                     (__attribute__((address_space(3))) void*)(lds + base),
                                     16, 0, 0);
  }
}

// Generic weight-tile stage (DSTROWB = LDS row bytes). src already chunk-offset.
template <int DSTROWB>
__device__ __forceinline__ void glds_stage(char* lds, const unsigned short* src,
                                           int srcRowShorts, int bytes) {
  const int wv = threadIdx.x >> 6, l = threadIdx.x & 63;
  for (int base = wv * 1024; base < bytes; base += 8192) {
    const int off = base + l * 16;
    const int row = off / DSTROWB;
    const int slot = (off % DSTROWB) >> 4;
    const int ss = slot ^ (row & 7);
    const unsigned short* g = src + row * srcRowShorts + ss * 8;
    __builtin_amdgcn_global_load_lds((const __attribute__((address_space(1))) void*)g,
                                     (__attribute__((address_space(3))) void*)(lds + base),
                                     16, 0, 0);
  }
}

// 128x128 tile core over one BK=128 chunk (C=128 LDS tiles), 4 k-steps.
__device__ __forceinline__ void mm_core128(const char* AX, const char* BW, ffrag acc[2][4]) {
  const int wv = threadIdx.x >> 6;
  const int rh = wv >> 2, cq = wv & 3;
  #pragma unroll
  for (int ks = 0; ks < 4; ++ks) {
    const bfrag aw0 = ldfrag(BW, cq * 32, ks * 32, 128);
    const bfrag aw1 = ldfrag(BW, cq * 32 + 16, ks * 32, 128);
    #pragma unroll
    for (int nt = 0; nt < 4; ++nt) {
      const bfrag xb = ldfrag(AX, rh * 64 + nt * 16, ks * 32, 128);
      acc[0][nt] = MFMA16(aw0, xb, acc[0][nt]);
      acc[1][nt] = MFMA16(aw1, xb, acc[1][nt]);
    }
  }
}

// Wave-per-row LayerNorm: 4 elems/lane in, two packed bf16 words out.
__device__ __forceinline__ void ln_pack(float d0, float d1, float d2, float d3,
                                        const float* g, const float* bb, int lane,
                                        unsigned& o0, unsigned& o1) {
  float s = d0 + d1 + d2 + d3;
  #pragma unroll
  for (int o = 32; o; o >>= 1) s += __shfl_xor(s, o);
  const float mu = s * (1.f / 256.f);
  d0 -= mu; d1 -= mu; d2 -= mu; d3 -= mu;
  float q = d0 * d0 + d1 * d1 + d2 * d2 + d3 * d3;
  #pragma unroll
  for (int o = 32; o; o >>= 1) q += __shfl_xor(q, o);
  const float vv = q * (1.f / 256.f) + 1e-5f;
  float rs = rsqrtf(vv);
  rs = rs * (1.5f - 0.5f * vv * rs * rs);
  const float4 g4 = *(const float4*)(g + lane * 4);
  const float4 b4 = *(const float4*)(bb + lane * 4);
  o0 = pk2(d0 * rs * g4.x + b4.x, d1 * rs * g4.y + b4.y);
  o1 = pk2(d2 * rs * g4.z + b4.z, d3 * rs * g4.w + b4.w);
}

// LN1 for one batch-group: 8192 blocks x 8 rows.
__global__ __launch_bounds__(512) void ln1_k(const float* __restrict__ x,
    const float* __restrict__ g, const float* __restrict__ bb,
    unsigned short* __restrict__ XB, long rowOfs) {
  const int wv = threadIdx.x >> 6, l = threadIdx.x & 63;
  const long lrow = (long)blockIdx.x * 8 + wv;
  const float4 v = *(const float4*)(x + (rowOfs + lrow) * 256 + l * 4);
  unsigned o0, o1;
  ln_pack(v.x, v.y, v.z, v.w, g, bb, l, o0, o1);
  unsigned short* dp = XB + lrow * 256 + l * 4;
  *(unsigned*)dp = o0; *(unsigned*)(dp + 2) = o1;
}

// qkv GEMM for one group: grid (512, 6). BK=128 x2, 64KB LDS, 2 blocks/CU.
__global__ __launch_bounds__(512, 4) void gemm_qkv(const unsigned short* __restrict__ XB,
    const float* __restrict__ qkv_b, unsigned short* __restrict__ QKV) {
  __shared__ __align__(16) char smem[65536];
  char* AX = smem; char* BW = smem + 32768;
  const int mb = blockIdx.x, nb = blockIdx.y;
  ffrag acc[2][4];
  #pragma unroll
  for (int a = 0; a < 2; ++a)
    #pragma unroll
    for (int n = 0; n < 4; ++n) { ffrag z = {0.f, 0.f, 0.f, 0.f}; acc[a][n] = z; }
  #pragma unroll
  for (int kc = 0; kc < 2; ++kc) {
    stage128(AX, XB, (long)mb * 128, 256, kc * 128);
    stage128(BW, g_wt, (long)nb * 128, 256, kc * 128);
    __syncthreads();
    mm_core128(AX, BW, acc);
    __syncthreads();
  }
  const int l = threadIdx.x & 63, wv = threadIdx.x >> 6;
  const int rh = wv >> 2, cq = wv & 3;
  const float sc = (nb < 2) ? 0.17677669529663687f : 1.f;   // Q pre-scale
  #pragma unroll
  for (int mt = 0; mt < 2; ++mt) {
    const int cg = nb * 128 + cq * 32 + mt * 16 + ((l >> 4) << 2);
    const float4 bq = *(const float4*)(qkv_b + cg);
    #pragma unroll
    for (int nt = 0; nt < 4; ++nt) {
      const long row = (long)mb * 128 + rh * 64 + nt * 16 + (l & 15);
      unsigned short* dp = QKV + row * 768 + cg;
      *(unsigned*)dp       = pk2((acc[mt][nt][0] + bq.x) * sc, (acc[mt][nt][1] + bq.y) * sc);
      *(unsigned*)(dp + 2) = pk2((acc[mt][nt][2] + bq.z) * sc, (acc[mt][nt][3] + bq.w) * sc);
    }
  }
}

// proj GEMM: full M=262144, grid (2048, 2). BK=128 x2, 2 blocks/CU.
__global__ __launch_bounds__(512, 4) void gemm_proj(const unsigned short* __restrict__ O,
    const float* __restrict__ proj_b, unsigned short* __restrict__ outw) {
  __shared__ __align__(16) char smem[65536];
  char* AX = smem; char* BW = smem + 32768;
  const int mb = blockIdx.x, nb = blockIdx.y;
  ffrag acc[2][4];
  #pragma unroll
  for (int a = 0; a < 2; ++a)
    #pragma unroll
    for (int n = 0; n < 4; ++n) { ffrag z = {0.f, 0.f, 0.f, 0.f}; acc[a][n] = z; }
  #pragma unroll
  for (int kc = 0; kc < 2; ++kc) {
    stage128(AX, O, (long)mb * 128, 256, kc * 128);
    stage128(BW, g_wt + 196608, (long)nb * 128, 256, kc * 128);
    __syncthreads();
    mm_core128(AX, BW, acc);
    __syncthreads();
  }
  const int l = threadIdx.x & 63, wv = threadIdx.x >> 6;
  const int rh = wv >> 2, cq = wv & 3;
  #pragma unroll
  for (int mt = 0; mt < 2; ++mt) {
    const int cg = nb * 128 + cq * 32 + mt * 16 + ((l >> 4) << 2);
    const float4 pb = *(const float4*)(proj_b + cg);
    #pragma unroll
    for (int nt = 0; nt < 4; ++nt) {
      const long row = (long)mb * 128 + rh * 64 + nt * 16 + (l & 15);
      unsigned short* dp = outw + row * 256 + cg;
      *(unsigned*)dp       = pk2(acc[mt][nt][0] + pb.x, acc[mt][nt][1] + pb.y);
      *(unsigned*)(dp + 2) = pk2(acc[mt][nt][2] + pb.z, acc[mt][nt][3] + pb.w);
    }
  }
}

// ---- attention core: one block per 8x8 window (1024 blocks/group) ----
// LDS 80KB: KL[64][256] 32K | VT[256][64] 32K | PB 8 x [16][64] 16K  -> 2 blocks/CU
__global__ __launch_bounds__(512, 4) void attn_core(const unsigned short* __restrict__ QKV,
    const float* __restrict__ rpb, unsigned short* __restrict__ O, int bofs) {
  __shared__ __align__(16) char smem[81920];
  char* KL = smem;
  char* VT = smem + 32768;
  char* PB = smem + 65536;
  const int t = threadIdx.x, wv = t >> 6, l = t & 63;
  const int blk = blockIdx.x;
  const int b = blk >> 8, w = blk & 255;   // b = local batch 0..3
  const int wi = w >> 4, wj = w & 15;
  const int bi0 = wi * 8 + 4, bj0 = wj * 8 + 4;
  const ffrag ZERO4 = {0.f, 0.f, 0.f, 0.f};

  #define SROW(r) (((long)b << 14) + (((bi0 + ((r) >> 3)) & 127) << 7) + ((bj0 + ((r) & 7)) & 127))
  #define GROW(r) (((long)(bofs + b) << 14) + (((bi0 + ((r) >> 3)) & 127) << 7) + ((bj0 + ((r) & 7)) & 127))

  // stage K rows -> KL (swizzled via pre-swizzled source)
  #pragma unroll
  for (int p = 0; p < 4; ++p) {
    const int base = wv * 1024 + p * 8192;
    const int off = base + l * 16;
    const int kv = off >> 9;
    const int ss = ((off & 511) >> 4) ^ (kv & 7);
    const unsigned short* g = QKV + SROW(kv) * 768 + 256 + ss * 8;
    __builtin_amdgcn_global_load_lds((const __attribute__((address_space(1))) void*)g,
                                     (__attribute__((address_space(3))) void*)(KL + base),
                                     16, 0, 0);
  }

  // stage V -> VT transposed (packed b32 writes)
  {
    const int rp = t & 31, dh = t >> 5;              // row-pair, d-hextet
    const unsigned short* v0p = QKV + SROW(2 * rp) * 768 + 512 + dh * 16;
    const unsigned short* v1p = QKV + SROW(2 * rp + 1) * 768 + 512 + dh * 16;
    const bfrag a0 = *(const bfrag*)v0p, a1 = *(const bfrag*)(v0p + 8);
    const bfrag c0 = *(const bfrag*)v1p, c1 = *(const bfrag*)(v1p + 8);
    #pragma unroll
    for (int j = 0; j < 8; ++j) {
      const unsigned w0 = ((unsigned)(unsigned short)a0[j]) | (((unsigned)(unsigned short)c0[j]) << 16);
      const unsigned w1 = ((unsigned)(unsigned short)a1[j]) | (((unsigned)(unsigned short)c1[j]) << 16);
      *(unsigned*)(VT + swz(dh * 16 + j, 2 * rp, 64)) = w0;
      *(unsigned*)(VT + swz(dh * 16 + 8 + j, 2 * rp, 64)) = w1;
    }
  }
  __syncthreads();

  const int qt = wv & 3, hh = wv >> 2;
  char* myPB = PB + wv * 2048;
  const int colb = l & 15;
  const int rbase = qt * 16 + ((l >> 4) << 2);

  for (int i = 0; i < 4; ++i) {
    const int h = 2 * i + hh;
    const int hk = h * 32;
    const int qr = qt * 16 + (l & 15);
    const bfrag aq = *(const bfrag*)(QKV + SROW(qr) * 768 + hk + ((l >> 4) << 3));
    ffrag s[4];
    #pragma unroll
    for (int nt = 0; nt < 4; ++nt) {
      const bfrag bk = ldfrag(KL, nt * 16, hk, 256);
      s[nt] = MFMA16(aq, bk, ZERO4);
    }
    float pr[4][4], mx[4], sm[4];
    #pragma unroll
    for (int reg = 0; reg < 4; ++reg) mx[reg] = -3e38f;
    #pragma unroll
    for (int nt = 0; nt < 4; ++nt)
      #pragma unroll
      for (int reg = 0; reg < 4; ++reg) {
        const int rr = rbase + reg, cc = nt * 16 + colb;
        const int idx = ((rr >> 3) - (cc >> 3) + 7) * 15 + ((rr & 7) - (cc & 7) + 7);
        pr[nt][reg] = s[nt][reg] + rpb[idx * 8 + h];
        mx[reg] = fmaxf(mx[reg], pr[nt][reg]);
      }
    #pragma unroll
    for (int reg = 0; reg < 4; ++reg) {
      #pragma unroll
      for (int o = 1; o < 16; o <<= 1) mx[reg] = fmaxf(mx[reg], __shfl_xor(mx[reg], o));
      sm[reg] = 0.f;
    }
    #pragma unroll
    for (int nt = 0; nt < 4; ++nt)
      #pragma unroll
      for (int reg = 0; reg < 4; ++reg) {
        pr[nt][reg] = __expf(pr[nt][reg] - mx[reg]);
        sm[reg] += pr[nt][reg];
      }
    #pragma unroll
    for (int reg = 0; reg < 4; ++reg) {
      #pragma unroll
      for (int o = 1; o < 16; o <<= 1) sm[reg] += __shfl_xor(sm[reg], o);
      sm[reg] = 1.f / sm[reg];
    }
    #pragma unroll
    for (int nt = 0; nt < 4; ++nt)
      #pragma unroll
      for (int reg = 0; reg < 4; ++reg)
        *(unsigned short*)(myPB + swz(((l >> 4) << 2) + reg, nt * 16 + colb, 64)) =
            (unsigned short)bf16b(pr[nt][reg] * sm[reg]);

    ffrag o0 = ZERO4, o1 = ZERO4;
    #pragma unroll
    for (int ks = 0; ks < 2; ++ks) {
      const bfrag ap = ldfrag(myPB, 0, ks * 32, 64);
      const bfrag bv0 = ldfrag(VT, hk, ks * 32, 64);
      const bfrag bv1 = ldfrag(VT, hk + 16, ks * 32, 64);
      o0 = MFMA16(ap, bv0, o0);
      o1 = MFMA16(ap, bv1, o1);
    }
    #pragma unroll
    for (int reg = 0; reg < 4; ++reg) {
      const long orow = GROW(rbase + reg);
      O[orow * 256 + hk + colb] = (unsigned short)bf16b(o0[reg]);
      O[orow * 256 + hk + 16 + colb] = (unsigned short)bf16b(o1[reg]);
    }
  }
  #undef SROW
  #undef GROW
}

// ---- fused MLP. 4096 blocks x 64 rows, 2 blocks/CU ----
// LDS 73728B: H2[64][256] 32K | WS 32K | HD[64][64] 8K
__global__ __launch_bounds__(512, 4) void swin_mlp(
    const float* __restrict__ x, const unsigned short* __restrict__ outw,
    const float* __restrict__ ln2g, const float* __restrict__ ln2b,
    const float* __restrict__ b1, const float* __restrict__ b2,
    float* __restrict__ y)
{
  __shared__ __align__(16) char smem[73728];
  char* H2 = smem;
  char* WS = smem + 32768;
  char* HD = smem + 65536;
  const int t = threadIdx.x, wv = t >> 6, l = t & 63;
  const long base = (long)blockIdx.x << 6;

  #pragma unroll
  for (int i = 0; i < 8; ++i) {
    const int r = wv * 8 + i;
    const uint2 raw = *(const uint2*)(outw + (base + r) * 256 + l * 4);
    unsigned o0, o1;
    ln_pack(bf2f(raw.x & 0xFFFFu), bf2f(raw.x >> 16), bf2f(raw.y & 0xFFFFu), bf2f(raw.y >> 16),
            ln2g, ln2b, l, o0, o1);
    *(unsigned*)(H2 + swz(r, l * 4, 256)) = o0;
    *(unsigned*)(H2 + swz(r, l * 4 + 2, 256)) = o1;
  }
  __syncthreads();

  const int mq = wv >> 1, nq = (wv & 1) << 1;

  ffrag acc2[2][4];
  #pragma unroll
  for (int mt = 0; mt < 2; ++mt)
    #pragma unroll
    for (int nt = 0; nt < 4; ++nt) { ffrag z = {0.f, 0.f, 0.f, 0.f}; acc2[mt][nt] = z; }

  for (int ch = 0; ch < 16; ++ch) {
    glds_stage<512>(WS, g_wt + 262144 + ch * 64 * 256, 256, 32768);
    __syncthreads();
    ffrag a1[2];
    { ffrag z = {0.f, 0.f, 0.f, 0.f}; a1[0] = z; a1[1] = z; }
    #pragma unroll
    for (int ks = 0; ks < 8; ++ks) {
      const bfrag a = ldfrag(WS, mq * 16, ks * 32, 256);
      const bfrag bb0 = ldfrag(H2, nq * 16, ks * 32, 256);
      const bfrag bb1 = ldfrag(H2, (nq + 1) * 16, ks * 32, 256);
      a1[0] = MFMA16(a, bb0, a1[0]);
      a1[1] = MFMA16(a, bb1, a1[1]);
    }
    __syncthreads();   // WS(w1) reads done

    // issue w2 stage FIRST (async), then GELU VALU hides the load latency
    glds_stage<128>(WS, g_wt + 524288 + ch * 64, 1024, 32768);
    const int c0 = mq * 16 + ((l >> 4) << 2);
    const float4 b14 = *(const float4*)(b1 + ch * 64 + c0);
    #pragma unroll
    for (int nt = 0; nt < 2; ++nt) {
      const int rr = (nq + nt) * 16 + (l & 15);
      const float g0 = gelu_t(a1[nt][0] + b14.x);
      const float g1 = gelu_t(a1[nt][1] + b14.y);
      const float g2 = gelu_t(a1[nt][2] + b14.z);
      const float g3 = gelu_t(a1[nt][3] + b14.w);
      *(unsigned*)(HD + swz(rr, c0, 64)) = pk2(g0, g1);
      *(unsigned*)(HD + swz(rr, c0 + 2, 64)) = pk2(g2, g3);
    }
    __syncthreads();

    #pragma unroll
    for (int ks = 0; ks < 2; ++ks) {
      const bfrag am0 = ldfrag(WS, (wv * 2) * 16, ks * 32, 64);
      const bfrag am1 = ldfrag(WS, (wv * 2 + 1) * 16, ks * 32, 64);
      #pragma unroll
      for (int nt = 0; nt < 4; ++nt) {
        const bfrag bb = ldfrag(HD, nt * 16, ks * 32, 64);
        acc2[0][nt] = MFMA16(am0, bb, acc2[0][nt]);
        acc2[1][nt] = MFMA16(am1, bb, acc2[1][nt]);
      }
    }
    __syncthreads();   // WS/HD reads done before next chunk
  }

  #pragma unroll
  for (int mt = 0; mt < 2; ++mt) {
    const int c0 = (wv * 2 + mt) * 16 + ((l >> 4) << 2);
    const float4 b24 = *(const float4*)(b2 + c0);
    #pragma unroll
    for (int nt = 0; nt < 4; ++nt) {
      const long row = base + nt * 16 + (l & 15);
      const float4 xv = *(const float4*)(x + row * 256 + c0);
      const uint2 ov = *(const uint2*)(outw + row * 256 + c0);
      float4 res;
      res.x = acc2[mt][nt][0] + b24.x + xv.x + bf2f(ov.x & 0xFFFFu);
      res.y = acc2[mt][nt][1] + b24.y + xv.y + bf2f(ov.x >> 16);
      res.z = acc2[mt][nt][2] + b24.z + xv.z + bf2f(ov.y & 0xFFFFu);
      res.w = acc2[mt][nt][3] + b24.w + xv.w + bf2f(ov.y >> 16);
      *(float4*)(y + row * 256 + c0) = res;
    }
  }
}

extern "C" void kernel_launch(void* const* d_in, const int* in_sizes, int n_in,
                              void* d_out, int out_size, void* d_ws, size_t ws_size,
                              hipStream_t stream) {
  (void)in_sizes; (void)n_in; (void)out_size; (void)ws_size;
  const float* x      = (const float*)d_in[0];
  const float* qkv_w  = (const float*)d_in[1];
  const float* qkv_b  = (const float*)d_in[2];
  const float* proj_w = (const float*)d_in[3];
  const float* proj_b = (const float*)d_in[4];
  const float* rpb    = (const float*)d_in[5];
  const float* ln1g   = (const float*)d_in[6];
  const float* ln1b   = (const float*)d_in[7];
  const float* ln2g   = (const float*)d_in[8];
  const float* ln2b   = (const float*)d_in[9];
  const float* w1     = (const float*)d_in[10];
  const float* b1     = (const float*)d_in[11];
  const float* w2     = (const float*)d_in[12];
  const float* b2     = (const float*)d_in[13];
  float* y = (float*)d_out;
  char* ws = (char*)d_ws;

  // Workspace (peak exactly 268,435,456 B):
  //   phase A (per 4-batch group): XB [0,32M) | QKV [32M,128M) | Obuf [128M,256M)
  //   phase B: outw bf16 [0,128M) over dead XB/QKV; Obuf consumed by proj.
  unsigned short* XB   = (unsigned short*)(ws);
  unsigned short* QKV  = (unsigned short*)(ws + 33554432);
  unsigned short* Obuf = (unsigned short*)(ws + 134217728);
  unsigned short* outw = (unsigned short*)(ws);

  hipLaunchKernelGGL(conv_w, dim3(1536), dim3(256), 0, stream, qkv_w, proj_w, w1, w2);
  for (int g = 0; g < 4; ++g) {
    hipLaunchKernelGGL(ln1_k, dim3(8192), dim3(512), 0, stream,
                       x, ln1g, ln1b, XB, (long)g * 65536);
    hipLaunchKernelGGL(gemm_qkv, dim3(512, 6), dim3(512), 0, stream, XB, qkv_b, QKV);
    hipLaunchKernelGGL(attn_core, dim3(1024), dim3(512), 0, stream, QKV, rpb, Obuf, g * 4);
  }
  hipLaunchKernelGGL(gemm_proj, dim3(2048, 2), dim3(512), 0, stream, Obuf, proj_b, outw);
  hipLaunchKernelGGL(swin_mlp, dim3(4096), dim3(512), 0, stream,
                     x, outw, ln2g, ln2b, b1, b2, y);
}